// Round 1
// baseline (559.780 us; speedup 1.0000x reference)
//
#include <hip/hip_runtime.h>
#include <hip/hip_bf16.h>
#include <cstdint>

typedef unsigned short u16;
typedef __attribute__((ext_vector_type(4))) float f32x4;
typedef __attribute__((ext_vector_type(8))) __bf16 bf16x8;

#define NH 16
#define NKV 4
#define SEQ 2048
#define NTOK 4096

__device__ inline u16 f2bf(float f) {
  return __builtin_bit_cast(u16, __float2bfloat16(f));
}
__device__ inline float bf2f(u16 u) {
  return __bfloat162float(__builtin_bit_cast(__hip_bfloat16, u));
}

#define GLDS(gp, lp) __builtin_amdgcn_global_load_lds( \
    (__attribute__((address_space(1))) void*)(gp), \
    (__attribute__((address_space(3))) void*)(lp), 16, 0, 0)

// ---------------- RMSNorm (f32 in, bf16 out) ----------------
__global__ __launch_bounds__(256) void rmsnorm_kernel(
    const float* __restrict__ x, const float* __restrict__ w,
    u16* __restrict__ out) {
  int row = blockIdx.x;
  int tid = threadIdx.x;
  const float4 v = reinterpret_cast<const float4*>(x + (size_t)row * 1024)[tid];
  float ss = v.x * v.x + v.y * v.y + v.z * v.z + v.w * v.w;
#pragma unroll
  for (int off = 32; off; off >>= 1) ss += __shfl_xor(ss, off);
  __shared__ float red[4];
  int lane = tid & 63, wid = tid >> 6;
  if (lane == 0) red[wid] = ss;
  __syncthreads();
  float tot = red[0] + red[1] + red[2] + red[3];
  float r = rsqrtf(tot * (1.0f / 1024.0f) + 1e-6f);
  const float4 wv = reinterpret_cast<const float4*>(w)[tid];
  ushort4 o;
  o.x = f2bf(v.x * r * wv.x);
  o.y = f2bf(v.y * r * wv.y);
  o.z = f2bf(v.z * r * wv.z);
  o.w = f2bf(v.w * r * wv.w);
  reinterpret_cast<ushort4*>(out + (size_t)row * 1024)[tid] = o;
}

// ---------------- weight transpose + cast: src[K][N] f32 -> dst[N][K] bf16 ----------------
__global__ __launch_bounds__(256) void transpose_cast_kernel(
    const float* __restrict__ src, u16* __restrict__ dst, int K, int N) {
  __shared__ float tile[32][33];
  int n0 = blockIdx.x * 32, k0 = blockIdx.y * 32;
  int tx = threadIdx.x & 31, ty = threadIdx.x >> 5;  // ty: 0..7
#pragma unroll
  for (int i = 0; i < 4; i++)
    tile[ty + i * 8][tx] = src[(size_t)(k0 + ty + i * 8) * N + n0 + tx];
  __syncthreads();
#pragma unroll
  for (int i = 0; i < 4; i++)
    dst[(size_t)(n0 + ty + i * 8) * K + k0 + tx] = f2bf(tile[tx][ty + i * 8]);
}

// ---------------- GEMM: C[M][N] = A[M][K](bf16) * Bt[N][K]^T (bf16), f32 acc ----------------
// EP 0: outf = acc (f32)
// EP 1: outf = res + acc*scale[col] (f32)
// EP 2: outb = bf16(silu(acc))
// EP 3: outb = bf16(bf2f(outb) * acc)   (RMW)
template <int EP>
__global__ __launch_bounds__(256) void gemm_bt(
    const u16* __restrict__ A, const u16* __restrict__ Bt,
    int M, int N, int K,
    float* __restrict__ outf, const float* __restrict__ res,
    const float* __restrict__ scale, u16* __restrict__ outb) {
  __shared__ u16 As[128][32];
  __shared__ u16 Bs[128][32];
  const int tid = threadIdx.x;
  const int lane = tid & 63;
  const int wid = tid >> 6;
  const int lg = lane >> 4, lc = lane & 15;
  const int wm = wid >> 1, wn = wid & 1;
  const int bm = blockIdx.y * 128, bn = blockIdx.x * 128;

  f32x4 acc[4][4] = {};

  const int r = tid >> 2;
  const int cb = (tid & 3) * 8;
  const u16* Ag = A + (size_t)(bm + r) * K + cb;
  const u16* Bg = Bt + (size_t)(bn + r) * K + cb;
  char* AsB = (char*)&As[0][0] + wid * 1024;
  char* BsB = (char*)&Bs[0][0] + wid * 1024;
  const size_t rowskip = (size_t)64 * K;

  for (int kt = 0; kt < K; kt += 32) {
    GLDS(Ag + kt, AsB);
    GLDS(Ag + kt + rowskip, AsB + 4096);
    GLDS(Bg + kt, BsB);
    GLDS(Bg + kt + rowskip, BsB + 4096);
    __syncthreads();
    bf16x8 afr[4], bfr[4];
#pragma unroll
    for (int i = 0; i < 4; i++) {
      afr[i] = *reinterpret_cast<const bf16x8*>(&As[wm * 64 + i * 16 + lc][lg * 8]);
      bfr[i] = *reinterpret_cast<const bf16x8*>(&Bs[wn * 64 + i * 16 + lc][lg * 8]);
    }
#pragma unroll
    for (int mi = 0; mi < 4; mi++)
#pragma unroll
      for (int ni = 0; ni < 4; ni++)
        acc[mi][ni] = __builtin_amdgcn_mfma_f32_16x16x32_bf16(afr[mi], bfr[ni], acc[mi][ni], 0, 0, 0);
    __syncthreads();
  }

#pragma unroll
  for (int mi = 0; mi < 4; mi++)
#pragma unroll
    for (int ni = 0; ni < 4; ni++)
#pragma unroll
      for (int rg = 0; rg < 4; rg++) {
        int row = bm + wm * 64 + mi * 16 + lg * 4 + rg;
        int col = bn + wn * 64 + ni * 16 + lc;
        size_t idx = (size_t)row * N + col;
        float v = acc[mi][ni][rg];
        if (EP == 0) {
          outf[idx] = v;
        } else if (EP == 1) {
          outf[idx] = res[idx] + v * scale[col];
        } else if (EP == 2) {
          outb[idx] = f2bf(v / (1.0f + __expf(-v)));
        } else {
          outb[idx] = f2bf(bf2f(outb[idx]) * v);
        }
      }
}

// ---------------- RoPE: qkv f32 -> q_rope [b][h][s][64] bf16, k_rope [b][kv][s][64] bf16 ----------------
__global__ __launch_bounds__(256) void rope_kernel(
    const float* __restrict__ qkv, const float* __restrict__ cosb,
    const float* __restrict__ sinb, u16* __restrict__ qr, u16* __restrict__ kr) {
  int idx = blockIdx.x * 256 + threadIdx.x;  // B*S*20*32 total
  int d = idx & 31;
  int t = idx >> 5;
  int head = t % 20;
  int bs = t / 20;  // 0..4095
  int s = bs & (SEQ - 1);
  int b = bs >> 11;
  const float* row = qkv + (size_t)bs * 1536;
  float c = cosb[s * 32 + d], sn = sinb[s * 32 + d];
  float x1, x2;
  u16 *o1, *o2;
  if (head < 16) {
    x1 = row[head * 64 + d];
    x2 = row[head * 64 + d + 32];
    size_t o = ((size_t)(b * NH + head) * SEQ + s) * 64 + d;
    o1 = qr + o;
    o2 = qr + o + 32;
  } else {
    int kh = head - 16;
    x1 = row[1024 + kh * 64 + d];
    x2 = row[1024 + kh * 64 + d + 32];
    size_t o = ((size_t)(b * NKV + kh) * SEQ + s) * 64 + d;
    o1 = kr + o;
    o2 = kr + o + 32;
  }
  *o1 = f2bf(x1 * c + x2 * sn);
  *o2 = f2bf(x2 * c - x1 * sn);
}

// ---------------- V transpose: qkv[.,1280+kv*64+d] f32 -> vt [b][kv][d][s] bf16 ----------------
__global__ __launch_bounds__(256) void vtrans_kernel(
    const float* __restrict__ qkv, u16* __restrict__ vt) {
  int blk = blockIdx.x;
  int st = blk & 31; blk >>= 5;
  int kvh = blk & 3; blk >>= 2;
  int b = blk;
  __shared__ u16 tile[64][65];
  int tx = threadIdx.x & 63;
  int ty = threadIdx.x >> 6;  // 0..3
  int s0 = st * 64;
#pragma unroll
  for (int i = 0; i < 16; i++) {
    int sl = i * 4 + ty;
    tile[sl][tx] = f2bf(qkv[(size_t)(b * SEQ + s0 + sl) * 1536 + 1280 + kvh * 64 + tx]);
  }
  __syncthreads();
  size_t vbase = (size_t)(b * NKV + kvh) * 64 * SEQ;
#pragma unroll
  for (int i = 0; i < 16; i++) {
    int dd = i * 4 + ty;
    vt[vbase + (size_t)dd * SEQ + s0 + tx] = tile[tx][dd];
  }
}

// ---------------- Flash attention (causal, GQA 4:1), bf16 MFMA ----------------
__global__ __launch_bounds__(256) void attn_kernel(
    const u16* __restrict__ qr, const u16* __restrict__ kr,
    const u16* __restrict__ vt, u16* __restrict__ out) {
  int blk = blockIdx.x;
  int qb = blk & 31; blk >>= 5;
  int h = blk & 15; blk >>= 4;
  int b = blk;
  int kvh = h >> 2;
  int tid = threadIdx.x, lane = tid & 63, w = tid >> 6;
  int lg = lane >> 4;  // 0..3
  int lc = lane & 15;
  __shared__ u16 plds[4][16][72];

  const int q0 = qb * 64 + w * 16;  // this wave's 16 q rows
  const u16* qrow = qr + ((size_t)(b * NH + h) * SEQ + q0 + lc) * 64;
  bf16x8 qf[2];
  qf[0] = *reinterpret_cast<const bf16x8*>(qrow + lg * 8);
  qf[1] = *reinterpret_cast<const bf16x8*>(qrow + 32 + lg * 8);

  const u16* kbase = kr + (size_t)(b * NKV + kvh) * SEQ * 64;
  const u16* vbase = vt + (size_t)(b * NKV + kvh) * 64 * SEQ;

  float mrun[4], lrun[4];
  f32x4 oacc[4] = {};
#pragma unroll
  for (int i = 0; i < 4; i++) { mrun[i] = -1e30f; lrun[i] = 0.0f; }

  const int nt = qb + 1;
  for (int t = 0; t < nt; t++) {
    int c0 = t * 64;
    f32x4 sc[4] = {};
#pragma unroll
    for (int ni = 0; ni < 4; ni++) {
      const u16* krow = kbase + (size_t)(c0 + ni * 16 + lc) * 64 + lg * 8;
      bf16x8 k0 = *reinterpret_cast<const bf16x8*>(krow);
      bf16x8 k1 = *reinterpret_cast<const bf16x8*>(krow + 32);
      sc[ni] = __builtin_amdgcn_mfma_f32_16x16x32_bf16(qf[0], k0, sc[ni], 0, 0, 0);
      sc[ni] = __builtin_amdgcn_mfma_f32_16x16x32_bf16(qf[1], k1, sc[ni], 0, 0, 0);
    }
    float p[4][4];
#pragma unroll
    for (int rg = 0; rg < 4; rg++) {
      int qi = q0 + lg * 4 + rg;
      float mx = -1e30f;
#pragma unroll
      for (int ni = 0; ni < 4; ni++) {
        int ki = c0 + ni * 16 + lc;
        float v = sc[ni][rg] * 0.125f;
        v = (ki <= qi) ? v : -1e30f;
        p[ni][rg] = v;
        mx = fmaxf(mx, v);
      }
#pragma unroll
      for (int off = 8; off; off >>= 1) mx = fmaxf(mx, __shfl_xor(mx, off));
      float mnew = fmaxf(mrun[rg], mx);
      float rs = 0.0f;
#pragma unroll
      for (int ni = 0; ni < 4; ni++) {
        float e = __expf(p[ni][rg] - mnew);
        p[ni][rg] = e;
        rs += e;
      }
#pragma unroll
      for (int off = 8; off; off >>= 1) rs += __shfl_xor(rs, off);
      float alpha = __expf(mrun[rg] - mnew);
      lrun[rg] = lrun[rg] * alpha + rs;
      mrun[rg] = mnew;
#pragma unroll
      for (int dt = 0; dt < 4; dt++) oacc[dt][rg] *= alpha;
    }
#pragma unroll
    for (int ni = 0; ni < 4; ni++)
#pragma unroll
      for (int rg = 0; rg < 4; rg++)
        plds[w][lg * 4 + rg][ni * 16 + lc] = f2bf(p[ni][rg]);
#pragma unroll
    for (int ks = 0; ks < 2; ks++) {
      bf16x8 pa = *reinterpret_cast<const bf16x8*>(&plds[w][lc][ks * 32 + lg * 8]);
#pragma unroll
      for (int dt = 0; dt < 4; dt++) {
        const u16* vrow = vbase + (size_t)(dt * 16 + lc) * SEQ + c0 + ks * 32 + lg * 8;
        bf16x8 vb = *reinterpret_cast<const bf16x8*>(vrow);
        oacc[dt] = __builtin_amdgcn_mfma_f32_16x16x32_bf16(pa, vb, oacc[dt], 0, 0, 0);
      }
    }
  }
#pragma unroll
  for (int dt = 0; dt < 4; dt++)
#pragma unroll
    for (int rg = 0; rg < 4; rg++) {
      int q = q0 + lg * 4 + rg;
      out[(size_t)(b * SEQ + q) * 1024 + h * 64 + dt * 16 + lc] = f2bf(oacc[dt][rg] / lrun[rg]);
    }
}

extern "C" void kernel_launch(void* const* d_in, const int* in_sizes, int n_in,
                              void* d_out, int out_size, void* d_ws, size_t ws_size,
                              hipStream_t stream) {
  const float* x = (const float*)d_in[0];
  const float* w_norm1 = (const float*)d_in[1];
  const float* wq = (const float*)d_in[2];
  const float* wk = (const float*)d_in[3];
  const float* wv = (const float*)d_in[4];
  const float* wo = (const float*)d_in[5];
  const float* attn_scale = (const float*)d_in[6];
  const float* w_norm2 = (const float*)d_in[7];
  const float* wg = (const float*)d_in[8];
  const float* wu = (const float*)d_in[9];
  const float* wd = (const float*)d_in[10];
  const float* mlp_scale = (const float*)d_in[11];
  const float* cosb = (const float*)d_in[12];
  const float* sinb = (const float*)d_in[13];
  float* out = (float*)d_out;

  char* ws = (char*)d_ws;
  u16* wqkv_t = (u16*)(ws + 0);            // 1536x1024 bf16 = 3145728
  u16* wo_t = (u16*)(ws + 3145728);        // 1024x1024 bf16 = 2097152
  u16* wg_t = (u16*)(ws + 5242880);        // 4096x1024 bf16 = 8388608
  u16* wu_t = (u16*)(ws + 13631488);       // 8388608
  u16* wd_t = (u16*)(ws + 22020096);       // 1024x4096 bf16 = 8388608
  u16* xn = (u16*)(ws + 30408704);         // 4096x1024 bf16 = 8388608 (reused for xn2)
  float* qkv = (float*)(ws + 38797312);    // 4096x1536 f32 = 25165824
  u16* attn_o = (u16*)(ws + 38797312);     // alias (qkv dead): 4096x1024 bf16 = 8388608
  float* x1 = (float*)(ws + 47185920);     // alias: 4096x1024 f32 = 16777216
  u16* q_rope = (u16*)(ws + 63963136);     // 2*16*2048*64 bf16 = 8388608
  u16* k_rope = (u16*)(ws + 72351744);     // 2*4*2048*64 bf16 = 2097152
  u16* vt = (u16*)(ws + 74448896);         // 2*4*64*2048 bf16 = 2097152
  u16* hbuf = (u16*)(ws + 63963136);       // alias (rope dead in FFN phase): 4096x4096 bf16 = 33554432
  // total required: 97,517,568 bytes

  dim3 tb(256);
  // weight transposes + bf16 cast
  transpose_cast_kernel<<<dim3(32, 32), tb, 0, stream>>>(wq, wqkv_t, 1024, 1024);
  transpose_cast_kernel<<<dim3(8, 32), tb, 0, stream>>>(wk, wqkv_t + (size_t)1024 * 1024, 1024, 256);
  transpose_cast_kernel<<<dim3(8, 32), tb, 0, stream>>>(wv, wqkv_t + (size_t)1280 * 1024, 1024, 256);
  transpose_cast_kernel<<<dim3(32, 32), tb, 0, stream>>>(wo, wo_t, 1024, 1024);
  transpose_cast_kernel<<<dim3(128, 32), tb, 0, stream>>>(wg, wg_t, 1024, 4096);
  transpose_cast_kernel<<<dim3(128, 32), tb, 0, stream>>>(wu, wu_t, 1024, 4096);
  transpose_cast_kernel<<<dim3(32, 128), tb, 0, stream>>>(wd, wd_t, 4096, 1024);

  rmsnorm_kernel<<<4096, tb, 0, stream>>>(x, w_norm1, xn);
  gemm_bt<0><<<dim3(12, 32), tb, 0, stream>>>(xn, wqkv_t, 4096, 1536, 1024, qkv, nullptr, nullptr, nullptr);
  rope_kernel<<<10240, tb, 0, stream>>>(qkv, cosb, sinb, q_rope, k_rope);
  vtrans_kernel<<<2 * 4 * 32, tb, 0, stream>>>(qkv, vt);
  attn_kernel<<<2 * 16 * 32, tb, 0, stream>>>(q_rope, k_rope, vt, attn_o);
  gemm_bt<1><<<dim3(8, 32), tb, 0, stream>>>(attn_o, wo_t, 4096, 1024, 1024, x1, x, attn_scale, nullptr);
  rmsnorm_kernel<<<4096, tb, 0, stream>>>(x1, w_norm2, xn);
  gemm_bt<2><<<dim3(32, 32), tb, 0, stream>>>(xn, wg_t, 4096, 4096, 1024, nullptr, nullptr, nullptr, hbuf);
  gemm_bt<3><<<dim3(32, 32), tb, 0, stream>>>(xn, wu_t, 4096, 4096, 1024, nullptr, nullptr, nullptr, hbuf);
  gemm_bt<1><<<dim3(8, 32), tb, 0, stream>>>(hbuf, wd_t, 4096, 1024, 4096, out, x1, mlp_scale, nullptr);
}

// Round 2
// 458.104 us; speedup vs baseline: 1.2220x; 1.2220x over previous
//
#include <hip/hip_runtime.h>
#include <hip/hip_bf16.h>
#include <cstdint>

typedef unsigned short u16;
typedef __attribute__((ext_vector_type(4))) float f32x4;
typedef __attribute__((ext_vector_type(8))) __bf16 bf16x8;

#define NH 16
#define NKV 4
#define SEQ 2048
#define NTOK 4096

__device__ inline u16 f2bf(float f) {
  return __builtin_bit_cast(u16, __float2bfloat16(f));
}
__device__ inline float bf2f(u16 u) {
  return __bfloat162float(__builtin_bit_cast(__hip_bfloat16, u));
}

#define GLDS(gp, lp) __builtin_amdgcn_global_load_lds( \
    (__attribute__((address_space(1))) void*)(gp), \
    (__attribute__((address_space(3))) void*)(lp), 16, 0, 0)

// ---------------- RMSNorm (f32 in, bf16 out) ----------------
__global__ __launch_bounds__(256) void rmsnorm_kernel(
    const float* __restrict__ x, const float* __restrict__ w,
    u16* __restrict__ out) {
  int row = blockIdx.x;
  int tid = threadIdx.x;
  const float4 v = reinterpret_cast<const float4*>(x + (size_t)row * 1024)[tid];
  float ss = v.x * v.x + v.y * v.y + v.z * v.z + v.w * v.w;
#pragma unroll
  for (int off = 32; off; off >>= 1) ss += __shfl_xor(ss, off);
  __shared__ float red[4];
  int lane = tid & 63, wid = tid >> 6;
  if (lane == 0) red[wid] = ss;
  __syncthreads();
  float tot = red[0] + red[1] + red[2] + red[3];
  float r = rsqrtf(tot * (1.0f / 1024.0f) + 1e-6f);
  const float4 wv = reinterpret_cast<const float4*>(w)[tid];
  ushort4 o;
  o.x = f2bf(v.x * r * wv.x);
  o.y = f2bf(v.y * r * wv.y);
  o.z = f2bf(v.z * r * wv.z);
  o.w = f2bf(v.w * r * wv.w);
  reinterpret_cast<ushort4*>(out + (size_t)row * 1024)[tid] = o;
}

// ---------------- weight transpose + cast: src[K][N] f32 -> dst[N][K] bf16 ----------------
__global__ __launch_bounds__(256) void transpose_cast_kernel(
    const float* __restrict__ src, u16* __restrict__ dst, int K, int N) {
  __shared__ float tile[32][33];
  int n0 = blockIdx.x * 32, k0 = blockIdx.y * 32;
  int tx = threadIdx.x & 31, ty = threadIdx.x >> 5;  // ty: 0..7
#pragma unroll
  for (int i = 0; i < 4; i++)
    tile[ty + i * 8][tx] = src[(size_t)(k0 + ty + i * 8) * N + n0 + tx];
  __syncthreads();
#pragma unroll
  for (int i = 0; i < 4; i++)
    dst[(size_t)(n0 + ty + i * 8) * K + k0 + tx] = f2bf(tile[tx][ty + i * 8]);
}

// ---------------- GEMM: C[M][N] = A[M][K](bf16) * Bt[N][K]^T (bf16), f32 acc ----------------
template <int EP>
__global__ __launch_bounds__(256) void gemm_bt(
    const u16* __restrict__ A, const u16* __restrict__ Bt,
    int M, int N, int K,
    float* __restrict__ outf, const float* __restrict__ res,
    const float* __restrict__ scale, u16* __restrict__ outb) {
  __shared__ u16 As[128][32];
  __shared__ u16 Bs[128][32];
  const int tid = threadIdx.x;
  const int lane = tid & 63;
  const int wid = tid >> 6;
  const int lg = lane >> 4, lc = lane & 15;
  const int wm = wid >> 1, wn = wid & 1;
  const int bm = blockIdx.y * 128, bn = blockIdx.x * 128;

  f32x4 acc[4][4] = {};

  const int r = tid >> 2;
  const int cb = (tid & 3) * 8;
  const u16* Ag = A + (size_t)(bm + r) * K + cb;
  const u16* Bg = Bt + (size_t)(bn + r) * K + cb;
  char* AsB = (char*)&As[0][0] + wid * 1024;
  char* BsB = (char*)&Bs[0][0] + wid * 1024;
  const size_t rowskip = (size_t)64 * K;

  for (int kt = 0; kt < K; kt += 32) {
    GLDS(Ag + kt, AsB);
    GLDS(Ag + kt + rowskip, AsB + 4096);
    GLDS(Bg + kt, BsB);
    GLDS(Bg + kt + rowskip, BsB + 4096);
    __syncthreads();
    bf16x8 afr[4], bfr[4];
#pragma unroll
    for (int i = 0; i < 4; i++) {
      afr[i] = *reinterpret_cast<const bf16x8*>(&As[wm * 64 + i * 16 + lc][lg * 8]);
      bfr[i] = *reinterpret_cast<const bf16x8*>(&Bs[wn * 64 + i * 16 + lc][lg * 8]);
    }
#pragma unroll
    for (int mi = 0; mi < 4; mi++)
#pragma unroll
      for (int ni = 0; ni < 4; ni++)
        acc[mi][ni] = __builtin_amdgcn_mfma_f32_16x16x32_bf16(afr[mi], bfr[ni], acc[mi][ni], 0, 0, 0);
    __syncthreads();
  }

#pragma unroll
  for (int mi = 0; mi < 4; mi++)
#pragma unroll
    for (int ni = 0; ni < 4; ni++)
#pragma unroll
      for (int rg = 0; rg < 4; rg++) {
        int row = bm + wm * 64 + mi * 16 + lg * 4 + rg;
        int col = bn + wn * 64 + ni * 16 + lc;
        size_t idx = (size_t)row * N + col;
        float v = acc[mi][ni][rg];
        if (EP == 0) {
          outf[idx] = v;
        } else if (EP == 1) {
          outf[idx] = res[idx] + v * scale[col];
        } else if (EP == 2) {
          outb[idx] = f2bf(v / (1.0f + __expf(-v)));
        } else {
          outb[idx] = f2bf(bf2f(outb[idx]) * v);
        }
      }
}

// ---------------- RoPE: qkv f32 -> q_rope (pre-scaled by 0.125*log2e) bf16, k_rope bf16 ----------------
__global__ __launch_bounds__(256) void rope_kernel(
    const float* __restrict__ qkv, const float* __restrict__ cosb,
    const float* __restrict__ sinb, u16* __restrict__ qr, u16* __restrict__ kr) {
  int idx = blockIdx.x * 256 + threadIdx.x;  // B*S*20*32 total
  int d = idx & 31;
  int t = idx >> 5;
  int head = t % 20;
  int bs = t / 20;  // 0..4095
  int s = bs & (SEQ - 1);
  int b = bs >> 11;
  const float* row = qkv + (size_t)bs * 1536;
  float c = cosb[s * 32 + d], sn = sinb[s * 32 + d];
  const float QSC = 0.18033688011112042f;  // 0.125 * log2(e)
  float x1, x2;
  if (head < 16) {
    x1 = row[head * 64 + d];
    x2 = row[head * 64 + d + 32];
    size_t o = ((size_t)(b * NH + head) * SEQ + s) * 64 + d;
    qr[o] = f2bf((x1 * c + x2 * sn) * QSC);
    qr[o + 32] = f2bf((x2 * c - x1 * sn) * QSC);
  } else {
    int kh = head - 16;
    x1 = row[1024 + kh * 64 + d];
    x2 = row[1024 + kh * 64 + d + 32];
    size_t o = ((size_t)(b * NKV + kh) * SEQ + s) * 64 + d;
    kr[o] = f2bf(x1 * c + x2 * sn);
    kr[o + 32] = f2bf(x2 * c - x1 * sn);
  }
}

// ---------------- V transpose: qkv f32 -> vt [b][kv][d][s] bf16 ----------------
__global__ __launch_bounds__(256) void vtrans_kernel(
    const float* __restrict__ qkv, u16* __restrict__ vt) {
  int blk = blockIdx.x;
  int st = blk & 31; blk >>= 5;
  int kvh = blk & 3; blk >>= 2;
  int b = blk;
  __shared__ u16 tile[64][65];
  int tx = threadIdx.x & 63;
  int ty = threadIdx.x >> 6;  // 0..3
  int s0 = st * 64;
#pragma unroll
  for (int i = 0; i < 16; i++) {
    int sl = i * 4 + ty;
    tile[sl][tx] = f2bf(qkv[(size_t)(b * SEQ + s0 + sl) * 1536 + 1280 + kvh * 64 + tx]);
  }
  __syncthreads();
  size_t vbase = (size_t)(b * NKV + kvh) * 64 * SEQ;
#pragma unroll
  for (int i = 0; i < 16; i++) {
    int dd = i * 4 + ty;
    vt[vbase + (size_t)dd * SEQ + s0 + tx] = tile[tx][dd];
  }
}

// ---------------- Flash attention: 1 wave/block, 16 q-rows/wave, swapped QK^T ----------------
// Q pre-scaled by 0.125*log2e; softmax in exp2 domain.
__global__ __launch_bounds__(64, 4) void attn_kernel(
    const u16* __restrict__ qr, const u16* __restrict__ kr,
    const u16* __restrict__ vt, u16* __restrict__ out) {
  const int n = blockIdx.x;
  const int bh = n & 31;           // interleave heads for L2 spread
  const int j = 127 - (n >> 5);    // q-block (16 rows), heavy-first
  const int h = bh & 15, b = bh >> 4;
  const int kvh = h >> 2;
  const int lane = threadIdx.x;
  const int lg = lane >> 4, lc = lane & 15;
  const int q0 = j * 16;

  __shared__ u16 plds[16][64];
  const int swz = (lc & 3) << 4;  // XOR on u16 col index (flips bits 4,5)

  // Q as B-operand: B[d][q] = Q[q0+lc][d], d = lg*8 + j (+32)
  const u16* qrow = qr + ((size_t)(b * NH + h) * SEQ + q0 + lc) * 64 + lg * 8;
  const bf16x8 qf0 = *reinterpret_cast<const bf16x8*>(qrow);
  const bf16x8 qf1 = *reinterpret_cast<const bf16x8*>(qrow + 32);

  const u16* kbase = kr + (size_t)(b * NKV + kvh) * SEQ * 64 + (size_t)lc * 64 + lg * 8;
  const u16* vbase = vt + ((size_t)(b * NKV + kvh) * 64 + lc) * SEQ + lg * 8;

  float m = -1e30f, l = 0.0f;      // stats for q = q0 + lc
  f32x4 oacc[4] = {};              // oacc[dt][rg]: q = q0+4*lg+rg, d = dt*16+lc

  const int F = q0 >> 6;           // number of fully-unmasked 64-key tiles

  for (int t = 0; t <= F; ++t) {
    const int c0 = t * 64;
    const bool mask = (t == F);

    // K frags (A-operand): A[key][d], key = c0+ni*16+lc, d = lg*8+j (+32)
    bf16x8 kf[4][2];
#pragma unroll
    for (int ni = 0; ni < 4; ni++) {
      const u16* kp = kbase + (size_t)(c0 + ni * 16) * 64;
      kf[ni][0] = *reinterpret_cast<const bf16x8*>(kp);
      kf[ni][1] = *reinterpret_cast<const bf16x8*>(kp + 32);
    }
    f32x4 sc[4] = {};
#pragma unroll
    for (int ni = 0; ni < 4; ni++) {
      sc[ni] = __builtin_amdgcn_mfma_f32_16x16x32_bf16(kf[ni][0], qf0, sc[ni], 0, 0, 0);
      sc[ni] = __builtin_amdgcn_mfma_f32_16x16x32_bf16(kf[ni][1], qf1, sc[ni], 0, 0, 0);
    }

    // V frags (B-operand) issued early to hide under softmax
    bf16x8 vf[4][2];
#pragma unroll
    for (int dt = 0; dt < 4; dt++)
#pragma unroll
      for (int ks = 0; ks < 2; ks++)
        vf[dt][ks] = *reinterpret_cast<const bf16x8*>(
            vbase + (size_t)dt * 16 * SEQ + c0 + ks * 32);

    // lane holds S^T[key=c0+16ni+4lg+rg][q=q0+lc] in sc[ni][rg]
    if (mask) {
      const int q = q0 + lc;
#pragma unroll
      for (int ni = 0; ni < 4; ni++)
#pragma unroll
        for (int rg = 0; rg < 4; rg++)
          if (c0 + ni * 16 + lg * 4 + rg > q) sc[ni][rg] = -1e30f;
    }

    float mx = -1e30f;
#pragma unroll
    for (int ni = 0; ni < 4; ni++)
#pragma unroll
      for (int rg = 0; rg < 4; rg++) mx = fmaxf(mx, sc[ni][rg]);
    mx = fmaxf(mx, __shfl_xor(mx, 16));
    mx = fmaxf(mx, __shfl_xor(mx, 32));

    // defer-max: only rescale when max grew by > 11.5 (log2 units ~= e^8)
    if (!__all(mx - m <= 11.5f)) {
      float mn = fmaxf(m, mx);
      float al = exp2f(m - mn);
      m = mn;
      l *= al;
#pragma unroll
      for (int rg = 0; rg < 4; rg++) {
        float a = __shfl(al, lg * 4 + rg);
#pragma unroll
        for (int dt = 0; dt < 4; dt++) oacc[dt][rg] *= a;
      }
    }

    float rs = 0.0f;
#pragma unroll
    for (int ni = 0; ni < 4; ni++)
#pragma unroll
      for (int rg = 0; rg < 4; rg++) {
        float p = exp2f(sc[ni][rg] - m);
        sc[ni][rg] = p;
        rs += p;
      }
    rs += __shfl_xor(rs, 16);
    rs += __shfl_xor(rs, 32);
    l += rs;

    // P^T -> bf16 -> LDS (packed b64 writes, XOR-swizzled)
#pragma unroll
    for (int ni = 0; ni < 4; ni++) {
      ushort4 pk;
      pk.x = f2bf(sc[ni][0]);
      pk.y = f2bf(sc[ni][1]);
      pk.z = f2bf(sc[ni][2]);
      pk.w = f2bf(sc[ni][3]);
      *reinterpret_cast<ushort4*>(&plds[lc][(ni * 16 + lg * 4) ^ swz]) = pk;
    }

    // PV: A = P[q][k] from LDS, B = V[k][d] frags
#pragma unroll
    for (int ks = 0; ks < 2; ks++) {
      bf16x8 pa = *reinterpret_cast<const bf16x8*>(&plds[lc][(ks * 32 + lg * 8) ^ swz]);
#pragma unroll
      for (int dt = 0; dt < 4; dt++)
        oacc[dt] = __builtin_amdgcn_mfma_f32_16x16x32_bf16(pa, vf[dt][ks], oacc[dt], 0, 0, 0);
    }
  }

  const float li = 1.0f / l;  // at q = q0+lc
#pragma unroll
  for (int rg = 0; rg < 4; rg++) {
    float liq = __shfl(li, lg * 4 + rg);
    int q = q0 + lg * 4 + rg;
    u16* orow = out + (size_t)(b * SEQ + q) * 1024 + h * 64 + lc;
#pragma unroll
    for (int dt = 0; dt < 4; dt++)
      orow[dt * 16] = f2bf(oacc[dt][rg] * liq);
  }
}

extern "C" void kernel_launch(void* const* d_in, const int* in_sizes, int n_in,
                              void* d_out, int out_size, void* d_ws, size_t ws_size,
                              hipStream_t stream) {
  const float* x = (const float*)d_in[0];
  const float* w_norm1 = (const float*)d_in[1];
  const float* wq = (const float*)d_in[2];
  const float* wk = (const float*)d_in[3];
  const float* wv = (const float*)d_in[4];
  const float* wo = (const float*)d_in[5];
  const float* attn_scale = (const float*)d_in[6];
  const float* w_norm2 = (const float*)d_in[7];
  const float* wg = (const float*)d_in[8];
  const float* wu = (const float*)d_in[9];
  const float* wd = (const float*)d_in[10];
  const float* mlp_scale = (const float*)d_in[11];
  const float* cosb = (const float*)d_in[12];
  const float* sinb = (const float*)d_in[13];
  float* out = (float*)d_out;

  char* ws = (char*)d_ws;
  u16* wqkv_t = (u16*)(ws + 0);            // 1536x1024 bf16
  u16* wo_t = (u16*)(ws + 3145728);        // 1024x1024 bf16
  u16* wg_t = (u16*)(ws + 5242880);        // 4096x1024 bf16
  u16* wu_t = (u16*)(ws + 13631488);
  u16* wd_t = (u16*)(ws + 22020096);       // 1024x4096 bf16
  u16* xn = (u16*)(ws + 30408704);         // 4096x1024 bf16 (reused for xn2)
  float* qkv = (float*)(ws + 38797312);    // 4096x1536 f32
  u16* attn_o = (u16*)(ws + 38797312);     // alias (qkv dead)
  float* x1 = (float*)(ws + 47185920);     // 4096x1024 f32
  u16* q_rope = (u16*)(ws + 63963136);     // 2*16*2048*64 bf16
  u16* k_rope = (u16*)(ws + 72351744);     // 2*4*2048*64 bf16
  u16* vt = (u16*)(ws + 74448896);         // 2*4*64*2048 bf16
  u16* hbuf = (u16*)(ws + 63963136);       // alias (rope dead in FFN phase)

  dim3 tb(256);
  transpose_cast_kernel<<<dim3(32, 32), tb, 0, stream>>>(wq, wqkv_t, 1024, 1024);
  transpose_cast_kernel<<<dim3(8, 32), tb, 0, stream>>>(wk, wqkv_t + (size_t)1024 * 1024, 1024, 256);
  transpose_cast_kernel<<<dim3(8, 32), tb, 0, stream>>>(wv, wqkv_t + (size_t)1280 * 1024, 1024, 256);
  transpose_cast_kernel<<<dim3(32, 32), tb, 0, stream>>>(wo, wo_t, 1024, 1024);
  transpose_cast_kernel<<<dim3(128, 32), tb, 0, stream>>>(wg, wg_t, 1024, 4096);
  transpose_cast_kernel<<<dim3(128, 32), tb, 0, stream>>>(wu, wu_t, 1024, 4096);
  transpose_cast_kernel<<<dim3(32, 128), tb, 0, stream>>>(wd, wd_t, 4096, 1024);

  rmsnorm_kernel<<<4096, tb, 0, stream>>>(x, w_norm1, xn);
  gemm_bt<0><<<dim3(12, 32), tb, 0, stream>>>(xn, wqkv_t, 4096, 1536, 1024, qkv, nullptr, nullptr, nullptr);
  rope_kernel<<<10240, tb, 0, stream>>>(qkv, cosb, sinb, q_rope, k_rope);
  vtrans_kernel<<<2 * 4 * 32, tb, 0, stream>>>(qkv, vt);
  attn_kernel<<<4096, dim3(64), 0, stream>>>(q_rope, k_rope, vt, attn_o);
  gemm_bt<1><<<dim3(8, 32), tb, 0, stream>>>(attn_o, wo_t, 4096, 1024, 1024, x1, x, attn_scale, nullptr);
  rmsnorm_kernel<<<4096, tb, 0, stream>>>(x1, w_norm2, xn);
  gemm_bt<2><<<dim3(32, 32), tb, 0, stream>>>(xn, wg_t, 4096, 4096, 1024, nullptr, nullptr, nullptr, hbuf);
  gemm_bt<3><<<dim3(32, 32), tb, 0, stream>>>(xn, wu_t, 4096, 4096, 1024, nullptr, nullptr, nullptr, hbuf);
  gemm_bt<1><<<dim3(8, 32), tb, 0, stream>>>(hbuf, wd_t, 4096, 1024, 4096, out, x1, mlp_scale, nullptr);
}

// Round 3
// 397.318 us; speedup vs baseline: 1.4089x; 1.1530x over previous
//
#include <hip/hip_runtime.h>
#include <hip/hip_bf16.h>
#include <cstdint>

typedef unsigned short u16;
typedef __attribute__((ext_vector_type(4))) float f32x4;
typedef __attribute__((ext_vector_type(8))) __bf16 bf16x8;

#define NH 16
#define NKV 4
#define SEQ 2048
#define NTOK 4096

__device__ inline u16 f2bf(float f) {
  return __builtin_bit_cast(u16, __float2bfloat16(f));
}
__device__ inline float bf2f(u16 u) {
  return __bfloat162float(__builtin_bit_cast(__hip_bfloat16, u));
}

#define GLDS(gp, lp) __builtin_amdgcn_global_load_lds( \
    (__attribute__((address_space(1))) void*)(gp), \
    (__attribute__((address_space(3))) void*)(lp), 16, 0, 0)

// ---------------- RMSNorm (f32 in, bf16 out) ----------------
__global__ __launch_bounds__(256) void rmsnorm_kernel(
    const float* __restrict__ x, const float* __restrict__ w,
    u16* __restrict__ out) {
  int row = blockIdx.x;
  int tid = threadIdx.x;
  const float4 v = reinterpret_cast<const float4*>(x + (size_t)row * 1024)[tid];
  float ss = v.x * v.x + v.y * v.y + v.z * v.z + v.w * v.w;
#pragma unroll
  for (int off = 32; off; off >>= 1) ss += __shfl_xor(ss, off);
  __shared__ float red[4];
  int lane = tid & 63, wid = tid >> 6;
  if (lane == 0) red[wid] = ss;
  __syncthreads();
  float tot = red[0] + red[1] + red[2] + red[3];
  float r = rsqrtf(tot * (1.0f / 1024.0f) + 1e-6f);
  const float4 wv = reinterpret_cast<const float4*>(w)[tid];
  ushort4 o;
  o.x = f2bf(v.x * r * wv.x);
  o.y = f2bf(v.y * r * wv.y);
  o.z = f2bf(v.z * r * wv.z);
  o.w = f2bf(v.w * r * wv.w);
  reinterpret_cast<ushort4*>(out + (size_t)row * 1024)[tid] = o;
}

// ---------------- weight transpose + cast: src[K][N] f32 -> dst[N][K] bf16 ----------------
__global__ __launch_bounds__(256) void transpose_cast_kernel(
    const float* __restrict__ src, u16* __restrict__ dst, int K, int N) {
  __shared__ float tile[32][33];
  int n0 = blockIdx.x * 32, k0 = blockIdx.y * 32;
  int tx = threadIdx.x & 31, ty = threadIdx.x >> 5;  // ty: 0..7
#pragma unroll
  for (int i = 0; i < 4; i++)
    tile[ty + i * 8][tx] = src[(size_t)(k0 + ty + i * 8) * N + n0 + tx];
  __syncthreads();
#pragma unroll
  for (int i = 0; i < 4; i++)
    dst[(size_t)(n0 + ty + i * 8) * K + k0 + tx] = f2bf(tile[tx][ty + i * 8]);
}

// ---------------- GEMM: C[M][N] = A[M][K](bf16) * Bt[N][K]^T (bf16), f32 acc ----------------
template <int EP>
__global__ __launch_bounds__(256) void gemm_bt(
    const u16* __restrict__ A, const u16* __restrict__ Bt,
    int M, int N, int K,
    float* __restrict__ outf, const float* __restrict__ res,
    const float* __restrict__ scale, u16* __restrict__ outb) {
  __shared__ u16 As[128][32];
  __shared__ u16 Bs[128][32];
  const int tid = threadIdx.x;
  const int lane = tid & 63;
  const int wid = tid >> 6;
  const int lg = lane >> 4, lc = lane & 15;
  const int wm = wid >> 1, wn = wid & 1;
  const int bm = blockIdx.y * 128, bn = blockIdx.x * 128;

  f32x4 acc[4][4] = {};

  const int r = tid >> 2;
  const int cb = (tid & 3) * 8;
  const u16* Ag = A + (size_t)(bm + r) * K + cb;
  const u16* Bg = Bt + (size_t)(bn + r) * K + cb;
  char* AsB = (char*)&As[0][0] + wid * 1024;
  char* BsB = (char*)&Bs[0][0] + wid * 1024;
  const size_t rowskip = (size_t)64 * K;

  for (int kt = 0; kt < K; kt += 32) {
    GLDS(Ag + kt, AsB);
    GLDS(Ag + kt + rowskip, AsB + 4096);
    GLDS(Bg + kt, BsB);
    GLDS(Bg + kt + rowskip, BsB + 4096);
    __syncthreads();
    bf16x8 afr[4], bfr[4];
#pragma unroll
    for (int i = 0; i < 4; i++) {
      afr[i] = *reinterpret_cast<const bf16x8*>(&As[wm * 64 + i * 16 + lc][lg * 8]);
      bfr[i] = *reinterpret_cast<const bf16x8*>(&Bs[wn * 64 + i * 16 + lc][lg * 8]);
    }
#pragma unroll
    for (int mi = 0; mi < 4; mi++)
#pragma unroll
      for (int ni = 0; ni < 4; ni++)
        acc[mi][ni] = __builtin_amdgcn_mfma_f32_16x16x32_bf16(afr[mi], bfr[ni], acc[mi][ni], 0, 0, 0);
    __syncthreads();
  }

#pragma unroll
  for (int mi = 0; mi < 4; mi++)
#pragma unroll
    for (int ni = 0; ni < 4; ni++)
#pragma unroll
      for (int rg = 0; rg < 4; rg++) {
        int row = bm + wm * 64 + mi * 16 + lg * 4 + rg;
        int col = bn + wn * 64 + ni * 16 + lc;
        size_t idx = (size_t)row * N + col;
        float v = acc[mi][ni][rg];
        if (EP == 0) {
          outf[idx] = v;
        } else if (EP == 1) {
          outf[idx] = res[idx] + v * scale[col];
        } else if (EP == 2) {
          outb[idx] = f2bf(v / (1.0f + __expf(-v)));
        } else {
          outb[idx] = f2bf(bf2f(outb[idx]) * v);
        }
      }
}

// ---------------- RoPE: qkv f32 -> q_rope (pre-scaled by 0.125*log2e) bf16, k_rope bf16 ----------------
__global__ __launch_bounds__(256) void rope_kernel(
    const float* __restrict__ qkv, const float* __restrict__ cosb,
    const float* __restrict__ sinb, u16* __restrict__ qr, u16* __restrict__ kr) {
  int idx = blockIdx.x * 256 + threadIdx.x;  // B*S*20*32 total
  int d = idx & 31;
  int t = idx >> 5;
  int head = t % 20;
  int bs = t / 20;  // 0..4095
  int s = bs & (SEQ - 1);
  int b = bs >> 11;
  const float* row = qkv + (size_t)bs * 1536;
  float c = cosb[s * 32 + d], sn = sinb[s * 32 + d];
  const float QSC = 0.18033688011112042f;  // 0.125 * log2(e)
  float x1, x2;
  if (head < 16) {
    x1 = row[head * 64 + d];
    x2 = row[head * 64 + d + 32];
    size_t o = ((size_t)(b * NH + head) * SEQ + s) * 64 + d;
    qr[o] = f2bf((x1 * c + x2 * sn) * QSC);
    qr[o + 32] = f2bf((x2 * c - x1 * sn) * QSC);
  } else {
    int kh = head - 16;
    x1 = row[1024 + kh * 64 + d];
    x2 = row[1024 + kh * 64 + d + 32];
    size_t o = ((size_t)(b * NKV + kh) * SEQ + s) * 64 + d;
    kr[o] = f2bf(x1 * c + x2 * sn);
    kr[o + 32] = f2bf(x2 * c - x1 * sn);
  }
}

// ---------------- V transpose: qkv f32 -> vt [b][kv][d][s] bf16 ----------------
__global__ __launch_bounds__(256) void vtrans_kernel(
    const float* __restrict__ qkv, u16* __restrict__ vt) {
  int blk = blockIdx.x;
  int st = blk & 31; blk >>= 5;
  int kvh = blk & 3; blk >>= 2;
  int b = blk;
  __shared__ u16 tile[64][65];
  int tx = threadIdx.x & 63;
  int ty = threadIdx.x >> 6;  // 0..3
  int s0 = st * 64;
#pragma unroll
  for (int i = 0; i < 16; i++) {
    int sl = i * 4 + ty;
    tile[sl][tx] = f2bf(qkv[(size_t)(b * SEQ + s0 + sl) * 1536 + 1280 + kvh * 64 + tx]);
  }
  __syncthreads();
  size_t vbase = (size_t)(b * NKV + kvh) * 64 * SEQ;
#pragma unroll
  for (int i = 0; i < 16; i++) {
    int dd = i * 4 + ty;
    vt[vbase + (size_t)dd * SEQ + s0 + tx] = tile[tx][dd];
  }
}

// ---------------- Flash attention v3: 4 waves/block, 32 q-rows/wave, LDS-staged K/V ----------------
// K/V double-buffered in LDS (global_load_lds, counted vmcnt), XOR-swizzled.
// Swapped QK^T (lane owns P^T column), softmax in exp2 domain, defer-max.
__global__ __launch_bounds__(256, 2) void attn_kernel(
    const u16* __restrict__ qr, const u16* __restrict__ kr,
    const u16* __restrict__ vt, u16* __restrict__ out) {
  __shared__ u16 Ks[2][64 * 64];   // [key][d], swizzled
  __shared__ u16 Vs[2][64 * 64];   // [d][key], swizzled
  __shared__ u16 Ps[4][32 * 64];   // per-wave P[q][key], swizzled

  const int n = blockIdx.x;
  const int g = n & 7, m = n >> 3;          // g = b*4+kvh -> XCD-aligned
  const int b = g >> 2, kvh = g & 3;
  const int h = kvh * 4 + (m & 3);
  const int i = m >> 2;                     // 0..15
  const int jb = (i >> 3) ? (15 - (i & 7)) : (i & 7);  // paired for CU balance

  const int tid = threadIdx.x;
  const int lane = tid & 63, w = tid >> 6;
  const int lg = lane >> 4, lc = lane & 15;
  const int lc7 = lc & 7;

  const int q0w = jb * 128 + w * 32;        // wave's first q row
  const int nt = 2 * jb + 2;

  // Q fragments (B-operand): qf[qt][half] = Q[q0w+qt*16+lc][half*32+lg*8 ..+7]
  bf16x8 qf[2][2];
  {
    const u16* qp = qr + ((size_t)(b * NH + h) * SEQ + q0w + lc) * 64 + lg * 8;
#pragma unroll
    for (int qt = 0; qt < 2; qt++) {
      qf[qt][0] = *reinterpret_cast<const bf16x8*>(qp + qt * 16 * 64);
      qf[qt][1] = *reinterpret_cast<const bf16x8*>(qp + qt * 16 * 64 + 32);
    }
  }
  // drain Q loads so in-loop vmcnt counting sees only GLDS ops
  asm volatile("s_waitcnt vmcnt(0)" ::: "memory");

  // staging source offsets (u16 units); LDS dest is linear, source pre-swizzled
  const int r = tid >> 3;                               // 0..31 (row within 32-row half)
  const int cswz = ((((tid & 7) << 4) ^ ((r & 7) << 4)) >> 1);
  const u16* ksrc = kr + (size_t)(b * NKV + kvh) * SEQ * 64 + r * 64 + cswz;
  const u16* vsrc = vt + ((size_t)(b * NKV + kvh) * 64 + r) * SEQ + cswz;
  u16* Pw = &Ps[w][0];

#define STAGE(bufi, t) do { \
    const u16* kp_ = ksrc + (size_t)(t) * 64 * 64; \
    const u16* vp_ = vsrc + (size_t)(t) * 64; \
    GLDS(kp_,                 &Ks[bufi][w * 512]); \
    GLDS(kp_ + 32 * 64,       &Ks[bufi][2048 + w * 512]); \
    GLDS(vp_,                 &Vs[bufi][w * 512]); \
    GLDS(vp_ + (size_t)32 * SEQ, &Vs[bufi][2048 + w * 512]); \
  } while (0)

  STAGE(0, 0);

  float mm[2] = {-1e30f, -1e30f}, ll[2] = {0.0f, 0.0f};
  f32x4 oacc[2][4] = {};  // [qt][dt]: q = q0w+qt*16+lg*4+rg, d = dt*16+lc

  int buf = 0;
  for (int t = 0; t < nt; ++t) {
    if (t + 1 < nt) {
      STAGE(buf ^ 1, t + 1);
      asm volatile("s_waitcnt vmcnt(4)" ::: "memory");
    } else {
      asm volatile("s_waitcnt vmcnt(0)" ::: "memory");
    }
    __builtin_amdgcn_s_barrier();
    __builtin_amdgcn_sched_barrier(0);

    const int c0 = t * 64;
    if (c0 <= q0w + 31) {
      // K frags (A-operand): kf[ni][hf] = K[c0+ni*16+lc][hf*32+lg*8 ..+7]
      bf16x8 kf[4][2];
#pragma unroll
      for (int ni = 0; ni < 4; ni++) {
        const int row = ni * 16 + lc;
#pragma unroll
        for (int hf = 0; hf < 2; hf++)
          kf[ni][hf] = *reinterpret_cast<const bf16x8*>(
              &Ks[buf][row * 64 + ((((hf * 64 + lg * 16)) ^ (lc7 << 4)) >> 1)]);
      }
      // QK^T (swapped): sc[ni][qt] = S^T[key 16][q 16]
      f32x4 sc[4][2] = {};
#pragma unroll
      for (int ni = 0; ni < 4; ni++)
#pragma unroll
        for (int qt = 0; qt < 2; qt++) {
          sc[ni][qt] = __builtin_amdgcn_mfma_f32_16x16x32_bf16(kf[ni][0], qf[qt][0], sc[ni][qt], 0, 0, 0);
          sc[ni][qt] = __builtin_amdgcn_mfma_f32_16x16x32_bf16(kf[ni][1], qf[qt][1], sc[ni][qt], 0, 0, 0);
        }
      // V frags (B-operand): vf[dt][ks] = V[c0+ks*32+lg*8 ..][dt*16+lc]
      bf16x8 vf[4][2];
#pragma unroll
      for (int dt = 0; dt < 4; dt++) {
        const int row = dt * 16 + lc;
#pragma unroll
        for (int ks = 0; ks < 2; ks++)
          vf[dt][ks] = *reinterpret_cast<const bf16x8*>(
              &Vs[buf][row * 64 + (((ks * 64 + lg * 16) ^ (lc7 << 4)) >> 1)]);
      }
      // causal mask (only on boundary tiles)
      if (c0 + 63 > q0w) {
#pragma unroll
        for (int qt = 0; qt < 2; qt++) {
          const int q = q0w + qt * 16 + lc;
#pragma unroll
          for (int ni = 0; ni < 4; ni++)
#pragma unroll
            for (int rg = 0; rg < 4; rg++)
              if (c0 + ni * 16 + lg * 4 + rg > q) sc[ni][qt][rg] = -1e30f;
        }
      }
      // online softmax (exp2 domain), defer-max
      float mx[2];
#pragma unroll
      for (int qt = 0; qt < 2; qt++) {
        float v = -1e30f;
#pragma unroll
        for (int ni = 0; ni < 4; ni++)
#pragma unroll
          for (int rg = 0; rg < 4; rg++) v = fmaxf(v, sc[ni][qt][rg]);
        v = fmaxf(v, __shfl_xor(v, 16));
        v = fmaxf(v, __shfl_xor(v, 32));
        mx[qt] = v;
      }
      if (!__all(mx[0] - mm[0] <= 11.5f && mx[1] - mm[1] <= 11.5f)) {
        float al[2];
#pragma unroll
        for (int qt = 0; qt < 2; qt++) {
          float mn = fmaxf(mm[qt], mx[qt]);
          al[qt] = exp2f(mm[qt] - mn);
          mm[qt] = mn;
          ll[qt] *= al[qt];
        }
#pragma unroll
        for (int qt = 0; qt < 2; qt++)
#pragma unroll
          for (int rg = 0; rg < 4; rg++) {
            float a = __shfl(al[qt], lg * 4 + rg);
#pragma unroll
            for (int dt = 0; dt < 4; dt++) oacc[qt][dt][rg] *= a;
          }
      }
#pragma unroll
      for (int qt = 0; qt < 2; qt++) {
        float rs = 0.0f;
#pragma unroll
        for (int ni = 0; ni < 4; ni++)
#pragma unroll
          for (int rg = 0; rg < 4; rg++) {
            float p = exp2f(sc[ni][qt][rg] - mm[qt]);
            sc[ni][qt][rg] = p;
            rs += p;
          }
        rs += __shfl_xor(rs, 16);
        rs += __shfl_xor(rs, 32);
        ll[qt] += rs;
      }
      // P^T -> bf16 -> per-wave LDS (swizzled)
#pragma unroll
      for (int qt = 0; qt < 2; qt++)
#pragma unroll
        for (int ni = 0; ni < 4; ni++) {
          ushort4 pk;
          pk.x = f2bf(sc[ni][qt][0]);
          pk.y = f2bf(sc[ni][qt][1]);
          pk.z = f2bf(sc[ni][qt][2]);
          pk.w = f2bf(sc[ni][qt][3]);
          *reinterpret_cast<ushort4*>(
              &Pw[(qt * 16 + lc) * 64 + (((ni * 32 + lg * 8) ^ (lc7 << 4)) >> 1)]) = pk;
        }
      // PV: oacc[qt][dt] += P[q][k] * V[k][d]
#pragma unroll
      for (int qt = 0; qt < 2; qt++)
#pragma unroll
        for (int ks = 0; ks < 2; ks++) {
          bf16x8 pa = *reinterpret_cast<const bf16x8*>(
              &Pw[(qt * 16 + lc) * 64 + (((ks * 64 + lg * 16) ^ (lc7 << 4)) >> 1)]);
#pragma unroll
          for (int dt = 0; dt < 4; dt++)
            oacc[qt][dt] = __builtin_amdgcn_mfma_f32_16x16x32_bf16(pa, vf[dt][ks], oacc[qt][dt], 0, 0, 0);
        }
    }
    asm volatile("s_waitcnt lgkmcnt(0)" ::: "memory");
    __builtin_amdgcn_s_barrier();
    __builtin_amdgcn_sched_barrier(0);
    buf ^= 1;
  }
#undef STAGE

#pragma unroll
  for (int qt = 0; qt < 2; qt++) {
    const float li = 1.0f / ll[qt];
#pragma unroll
    for (int rg = 0; rg < 4; rg++) {
      float liq = __shfl(li, lg * 4 + rg);
      int q = q0w + qt * 16 + lg * 4 + rg;
      u16* orow = out + (size_t)(b * SEQ + q) * 1024 + h * 64 + lc;
#pragma unroll
      for (int dt = 0; dt < 4; dt++)
        orow[dt * 16] = f2bf(oacc[qt][dt][rg] * liq);
    }
  }
}

extern "C" void kernel_launch(void* const* d_in, const int* in_sizes, int n_in,
                              void* d_out, int out_size, void* d_ws, size_t ws_size,
                              hipStream_t stream) {
  const float* x = (const float*)d_in[0];
  const float* w_norm1 = (const float*)d_in[1];
  const float* wq = (const float*)d_in[2];
  const float* wk = (const float*)d_in[3];
  const float* wv = (const float*)d_in[4];
  const float* wo = (const float*)d_in[5];
  const float* attn_scale = (const float*)d_in[6];
  const float* w_norm2 = (const float*)d_in[7];
  const float* wg = (const float*)d_in[8];
  const float* wu = (const float*)d_in[9];
  const float* wd = (const float*)d_in[10];
  const float* mlp_scale = (const float*)d_in[11];
  const float* cosb = (const float*)d_in[12];
  const float* sinb = (const float*)d_in[13];
  float* out = (float*)d_out;

  char* ws = (char*)d_ws;
  u16* wqkv_t = (u16*)(ws + 0);            // 1536x1024 bf16
  u16* wo_t = (u16*)(ws + 3145728);        // 1024x1024 bf16
  u16* wg_t = (u16*)(ws + 5242880);        // 4096x1024 bf16
  u16* wu_t = (u16*)(ws + 13631488);
  u16* wd_t = (u16*)(ws + 22020096);       // 1024x4096 bf16
  u16* xn = (u16*)(ws + 30408704);         // 4096x1024 bf16 (reused for xn2)
  float* qkv = (float*)(ws + 38797312);    // 4096x1536 f32
  u16* attn_o = (u16*)(ws + 38797312);     // alias (qkv dead)
  float* x1 = (float*)(ws + 47185920);     // 4096x1024 f32
  u16* q_rope = (u16*)(ws + 63963136);     // 2*16*2048*64 bf16
  u16* k_rope = (u16*)(ws + 72351744);     // 2*4*2048*64 bf16
  u16* vt = (u16*)(ws + 74448896);         // 2*4*64*2048 bf16
  u16* hbuf = (u16*)(ws + 63963136);       // alias (rope dead in FFN phase)

  dim3 tb(256);
  transpose_cast_kernel<<<dim3(32, 32), tb, 0, stream>>>(wq, wqkv_t, 1024, 1024);
  transpose_cast_kernel<<<dim3(8, 32), tb, 0, stream>>>(wk, wqkv_t + (size_t)1024 * 1024, 1024, 256);
  transpose_cast_kernel<<<dim3(8, 32), tb, 0, stream>>>(wv, wqkv_t + (size_t)1280 * 1024, 1024, 256);
  transpose_cast_kernel<<<dim3(32, 32), tb, 0, stream>>>(wo, wo_t, 1024, 1024);
  transpose_cast_kernel<<<dim3(128, 32), tb, 0, stream>>>(wg, wg_t, 1024, 4096);
  transpose_cast_kernel<<<dim3(128, 32), tb, 0, stream>>>(wu, wu_t, 1024, 4096);
  transpose_cast_kernel<<<dim3(32, 128), tb, 0, stream>>>(wd, wd_t, 4096, 1024);

  rmsnorm_kernel<<<4096, tb, 0, stream>>>(x, w_norm1, xn);
  gemm_bt<0><<<dim3(12, 32), tb, 0, stream>>>(xn, wqkv_t, 4096, 1536, 1024, qkv, nullptr, nullptr, nullptr);
  rope_kernel<<<10240, tb, 0, stream>>>(qkv, cosb, sinb, q_rope, k_rope);
  vtrans_kernel<<<2 * 4 * 32, tb, 0, stream>>>(qkv, vt);
  attn_kernel<<<512, tb, 0, stream>>>(q_rope, k_rope, vt, attn_o);
  gemm_bt<1><<<dim3(8, 32), tb, 0, stream>>>(attn_o, wo_t, 4096, 1024, 1024, x1, x, attn_scale, nullptr);
  rmsnorm_kernel<<<4096, tb, 0, stream>>>(x1, w_norm2, xn);
  gemm_bt<2><<<dim3(32, 32), tb, 0, stream>>>(xn, wg_t, 4096, 4096, 1024, nullptr, nullptr, nullptr, hbuf);
  gemm_bt<3><<<dim3(32, 32), tb, 0, stream>>>(xn, wu_t, 4096, 4096, 1024, nullptr, nullptr, nullptr, hbuf);
  gemm_bt<1><<<dim3(8, 32), tb, 0, stream>>>(hbuf, wd_t, 4096, 1024, 4096, out, x1, mlp_scale, nullptr);
}

// Round 4
// 387.673 us; speedup vs baseline: 1.4439x; 1.0249x over previous
//
#include <hip/hip_runtime.h>
#include <hip/hip_bf16.h>
#include <cstdint>

typedef unsigned short u16;
typedef __attribute__((ext_vector_type(4))) float f32x4;
typedef __attribute__((ext_vector_type(8))) __bf16 bf16x8;

#define NH 16
#define NKV 4
#define SEQ 2048
#define NTOK 4096

__device__ inline u16 f2bf(float f) {
  return __builtin_bit_cast(u16, __float2bfloat16(f));
}
__device__ inline float bf2f(u16 u) {
  return __bfloat162float(__builtin_bit_cast(__hip_bfloat16, u));
}

#define GLDS(gp, lp) __builtin_amdgcn_global_load_lds( \
    (__attribute__((address_space(1))) void*)(gp), \
    (__attribute__((address_space(3))) void*)(lp), 16, 0, 0)

// ---------------- RMSNorm (f32 in, bf16 out) ----------------
__global__ __launch_bounds__(256) void rmsnorm_kernel(
    const float* __restrict__ x, const float* __restrict__ w,
    u16* __restrict__ out) {
  int row = blockIdx.x;
  int tid = threadIdx.x;
  const float4 v = reinterpret_cast<const float4*>(x + (size_t)row * 1024)[tid];
  float ss = v.x * v.x + v.y * v.y + v.z * v.z + v.w * v.w;
#pragma unroll
  for (int off = 32; off; off >>= 1) ss += __shfl_xor(ss, off);
  __shared__ float red[4];
  int lane = tid & 63, wid = tid >> 6;
  if (lane == 0) red[wid] = ss;
  __syncthreads();
  float tot = red[0] + red[1] + red[2] + red[3];
  float r = rsqrtf(tot * (1.0f / 1024.0f) + 1e-6f);
  const float4 wv = reinterpret_cast<const float4*>(w)[tid];
  ushort4 o;
  o.x = f2bf(v.x * r * wv.x);
  o.y = f2bf(v.y * r * wv.y);
  o.z = f2bf(v.z * r * wv.z);
  o.w = f2bf(v.w * r * wv.w);
  reinterpret_cast<ushort4*>(out + (size_t)row * 1024)[tid] = o;
}

// ---------------- weight transpose + cast: src[K][N] f32 -> dst[N][K] bf16 ----------------
__global__ __launch_bounds__(256) void transpose_cast_kernel(
    const float* __restrict__ src, u16* __restrict__ dst, int K, int N) {
  __shared__ float tile[32][33];
  int n0 = blockIdx.x * 32, k0 = blockIdx.y * 32;
  int tx = threadIdx.x & 31, ty = threadIdx.x >> 5;  // ty: 0..7
#pragma unroll
  for (int i = 0; i < 4; i++)
    tile[ty + i * 8][tx] = src[(size_t)(k0 + ty + i * 8) * N + n0 + tx];
  __syncthreads();
#pragma unroll
  for (int i = 0; i < 4; i++)
    dst[(size_t)(n0 + ty + i * 8) * K + k0 + tx] = f2bf(tile[tx][ty + i * 8]);
}

// ---------------- GEMM 256x256, BK=64, 8 waves, 4-phase split, dbuf LDS ----------------
// A[M][K] bf16, Bt[N][K] bf16. EP: 0 f32 out; 1 res+acc*scale f32; 2 silu->bf16; 3 RMW mul bf16.
template <int EP>
__global__ __launch_bounds__(512, 2) void gemm256(
    const u16* __restrict__ A, const u16* __restrict__ Bt,
    int M, int N, int K,
    float* __restrict__ outf, const float* __restrict__ res,
    const float* __restrict__ scale, u16* __restrict__ outb) {
  __shared__ u16 SA[2][256 * 64];
  __shared__ u16 SB[2][256 * 64];

  const int tid = threadIdx.x;
  const int lane = tid & 63;
  const int wid = tid >> 6;            // 0..7
  const int wr = wid >> 2, wc = wid & 3;
  const int lg = lane >> 4, lc = lane & 15;
  const int cswz = (lc & 7) << 3;      // ds_read XOR (u16 units)

  // XCD-aware block swizzle (all grids are multiples of 8)
  const int nwg = gridDim.x;
  const int bid = blockIdx.x;
  const int swz = (bid & 7) * (nwg >> 3) + (bid >> 3);
  const int nbn = N >> 8;
  const int bm = (swz / nbn) << 8;
  const int bn = (swz % nbn) << 8;

  // staging geometry: wave stripe = 8 rows x 128B, lane covers 16B
  const int rl = lane >> 3;                        // row in stripe
  const int cbs = ((lane & 7) << 4) ^ (rl << 4);   // pre-swizzled byte col
  const u16* baseA = A + (size_t)(bm + rl) * K + (cbs >> 1);
  const u16* baseB = Bt + (size_t)(bn + rl) * K + (cbs >> 1);

  const int NT = K >> 6;
  f32x4 acc[8][4] = {};

  u16* sA0 = &SA[0][0];
  u16* sB0 = &SB[0][0];
  u16* sA1 = &SA[1][0];
  u16* sB1 = &SB[1][0];

  // prologue: stage tile 0 into buf 0
#pragma unroll
  for (int hj = 0; hj < 4; hj++) {
    const int stripe = (hj >> 1) * 16 + wid * 2 + (hj & 1);
    GLDS(baseA + (size_t)stripe * 8 * K, sA0 + stripe * 512);
    GLDS(baseB + (size_t)stripe * 8 * K, sB0 + stripe * 512);
  }
  asm volatile("s_waitcnt vmcnt(0)" ::: "memory");
  __builtin_amdgcn_s_barrier();

  int buf = 0;
  for (int t = 0; t < NT; ++t) {
    const u16* uA = buf ? sA1 : sA0;
    const u16* uB = buf ? sB1 : sB0;
    u16* nA = buf ? sA0 : sA1;
    u16* nB = buf ? sB0 : sB1;
    const int koff = (t + 1) << 6;
    const bool more = (t + 1 < NT);
#pragma unroll
    for (int p = 0; p < 4; ++p) {
      const int mb = (p >> 1) * 4, nb = (p & 1) * 2;
      bf16x8 af[4][2], bfr[2][2];
#pragma unroll
      for (int i = 0; i < 4; i++) {
        const int row = wr * 128 + (mb + i) * 16 + lc;
#pragma unroll
        for (int kk = 0; kk < 2; kk++)
          af[i][kk] = *reinterpret_cast<const bf16x8*>(
              &uA[row * 64 + ((kk * 32 + lg * 8) ^ cswz)]);
      }
#pragma unroll
      for (int j = 0; j < 2; j++) {
        const int row = wc * 64 + (nb + j) * 16 + lc;
#pragma unroll
        for (int kk = 0; kk < 2; kk++)
          bfr[j][kk] = *reinterpret_cast<const bf16x8*>(
              &uB[row * 64 + ((kk * 32 + lg * 8) ^ cswz)]);
      }
      // prefetch next K-tile into the other buffer (A during p0, B during p1)
      if (p == 0 && more) {
#pragma unroll
        for (int hj = 0; hj < 4; hj++) {
          const int stripe = (hj >> 1) * 16 + wid * 2 + (hj & 1);
          GLDS(baseA + (size_t)stripe * 8 * K + koff, nA + stripe * 512);
        }
      }
      if (p == 1 && more) {
#pragma unroll
        for (int hj = 0; hj < 4; hj++) {
          const int stripe = (hj >> 1) * 16 + wid * 2 + (hj & 1);
          GLDS(baseB + (size_t)stripe * 8 * K + koff, nB + stripe * 512);
        }
      }
      __builtin_amdgcn_s_barrier();
      __builtin_amdgcn_s_setprio(1);
#pragma unroll
      for (int i = 0; i < 4; i++)
#pragma unroll
        for (int j = 0; j < 2; j++)
#pragma unroll
          for (int kk = 0; kk < 2; kk++)
            acc[mb + i][nb + j] = __builtin_amdgcn_mfma_f32_16x16x32_bf16(
                af[i][kk], bfr[j][kk], acc[mb + i][nb + j], 0, 0, 0);
      __builtin_amdgcn_s_setprio(0);
    }
    asm volatile("s_waitcnt vmcnt(0)" ::: "memory");
    __builtin_amdgcn_s_barrier();
    buf ^= 1;
  }

#pragma unroll
  for (int mi = 0; mi < 8; mi++)
#pragma unroll
    for (int ni = 0; ni < 4; ni++)
#pragma unroll
      for (int rg = 0; rg < 4; rg++) {
        const int row = bm + wr * 128 + mi * 16 + lg * 4 + rg;
        const int col = bn + wc * 64 + ni * 16 + lc;
        const size_t idx = (size_t)row * N + col;
        const float v = acc[mi][ni][rg];
        if (EP == 0) {
          outf[idx] = v;
        } else if (EP == 1) {
          outf[idx] = res[idx] + v * scale[col];
        } else if (EP == 2) {
          outb[idx] = f2bf(v / (1.0f + __expf(-v)));
        } else {
          outb[idx] = f2bf(bf2f(outb[idx]) * v);
        }
      }
}

// ---------------- RoPE: qkv f32 -> q_rope (pre-scaled by 0.125*log2e) bf16, k_rope bf16 ----------------
__global__ __launch_bounds__(256) void rope_kernel(
    const float* __restrict__ qkv, const float* __restrict__ cosb,
    const float* __restrict__ sinb, u16* __restrict__ qr, u16* __restrict__ kr) {
  int idx = blockIdx.x * 256 + threadIdx.x;  // B*S*20*32 total
  int d = idx & 31;
  int t = idx >> 5;
  int head = t % 20;
  int bs = t / 20;  // 0..4095
  int s = bs & (SEQ - 1);
  int b = bs >> 11;
  const float* row = qkv + (size_t)bs * 1536;
  float c = cosb[s * 32 + d], sn = sinb[s * 32 + d];
  const float QSC = 0.18033688011112042f;  // 0.125 * log2(e)
  float x1, x2;
  if (head < 16) {
    x1 = row[head * 64 + d];
    x2 = row[head * 64 + d + 32];
    size_t o = ((size_t)(b * NH + head) * SEQ + s) * 64 + d;
    qr[o] = f2bf((x1 * c + x2 * sn) * QSC);
    qr[o + 32] = f2bf((x2 * c - x1 * sn) * QSC);
  } else {
    int kh = head - 16;
    x1 = row[1024 + kh * 64 + d];
    x2 = row[1024 + kh * 64 + d + 32];
    size_t o = ((size_t)(b * NKV + kh) * SEQ + s) * 64 + d;
    kr[o] = f2bf(x1 * c + x2 * sn);
    kr[o + 32] = f2bf(x2 * c - x1 * sn);
  }
}

// ---------------- V transpose: qkv f32 -> vt [b][kv][d][s] bf16 ----------------
__global__ __launch_bounds__(256) void vtrans_kernel(
    const float* __restrict__ qkv, u16* __restrict__ vt) {
  int blk = blockIdx.x;
  int st = blk & 31; blk >>= 5;
  int kvh = blk & 3; blk >>= 2;
  int b = blk;
  __shared__ u16 tile[64][65];
  int tx = threadIdx.x & 63;
  int ty = threadIdx.x >> 6;  // 0..3
  int s0 = st * 64;
#pragma unroll
  for (int i = 0; i < 16; i++) {
    int sl = i * 4 + ty;
    tile[sl][tx] = f2bf(qkv[(size_t)(b * SEQ + s0 + sl) * 1536 + 1280 + kvh * 64 + tx]);
  }
  __syncthreads();
  size_t vbase = (size_t)(b * NKV + kvh) * 64 * SEQ;
#pragma unroll
  for (int i = 0; i < 16; i++) {
    int dd = i * 4 + ty;
    vt[vbase + (size_t)dd * SEQ + s0 + tx] = tile[tx][dd];
  }
}

// ---------------- Flash attention v3: 4 waves/block, 32 q-rows/wave, LDS-staged K/V ----------------
__global__ __launch_bounds__(256, 2) void attn_kernel(
    const u16* __restrict__ qr, const u16* __restrict__ kr,
    const u16* __restrict__ vt, u16* __restrict__ out) {
  __shared__ u16 Ks[2][64 * 64];   // [key][d], swizzled
  __shared__ u16 Vs[2][64 * 64];   // [d][key], swizzled
  __shared__ u16 Ps[4][32 * 64];   // per-wave P[q][key], swizzled

  const int n = blockIdx.x;
  const int g = n & 7, m = n >> 3;          // g = b*4+kvh -> XCD-aligned
  const int b = g >> 2, kvh = g & 3;
  const int h = kvh * 4 + (m & 3);
  const int i = m >> 2;                     // 0..15
  const int jb = (i >> 3) ? (15 - (i & 7)) : (i & 7);  // paired for CU balance

  const int tid = threadIdx.x;
  const int lane = tid & 63, w = tid >> 6;
  const int lg = lane >> 4, lc = lane & 15;
  const int lc7 = lc & 7;

  const int q0w = jb * 128 + w * 32;        // wave's first q row
  const int nt = 2 * jb + 2;

  bf16x8 qf[2][2];
  {
    const u16* qp = qr + ((size_t)(b * NH + h) * SEQ + q0w + lc) * 64 + lg * 8;
#pragma unroll
    for (int qt = 0; qt < 2; qt++) {
      qf[qt][0] = *reinterpret_cast<const bf16x8*>(qp + qt * 16 * 64);
      qf[qt][1] = *reinterpret_cast<const bf16x8*>(qp + qt * 16 * 64 + 32);
    }
  }
  asm volatile("s_waitcnt vmcnt(0)" ::: "memory");

  const int r = tid >> 3;
  const int cswz = ((((tid & 7) << 4) ^ ((r & 7) << 4)) >> 1);
  const u16* ksrc = kr + (size_t)(b * NKV + kvh) * SEQ * 64 + r * 64 + cswz;
  const u16* vsrc = vt + ((size_t)(b * NKV + kvh) * 64 + r) * SEQ + cswz;
  u16* Pw = &Ps[w][0];

#define STAGE(bufi, t) do { \
    const u16* kp_ = ksrc + (size_t)(t) * 64 * 64; \
    const u16* vp_ = vsrc + (size_t)(t) * 64; \
    GLDS(kp_,                 &Ks[bufi][w * 512]); \
    GLDS(kp_ + 32 * 64,       &Ks[bufi][2048 + w * 512]); \
    GLDS(vp_,                 &Vs[bufi][w * 512]); \
    GLDS(vp_ + (size_t)32 * SEQ, &Vs[bufi][2048 + w * 512]); \
  } while (0)

  STAGE(0, 0);

  float mm[2] = {-1e30f, -1e30f}, ll[2] = {0.0f, 0.0f};
  f32x4 oacc[2][4] = {};

  int buf = 0;
  for (int t = 0; t < nt; ++t) {
    if (t + 1 < nt) {
      STAGE(buf ^ 1, t + 1);
      asm volatile("s_waitcnt vmcnt(4)" ::: "memory");
    } else {
      asm volatile("s_waitcnt vmcnt(0)" ::: "memory");
    }
    __builtin_amdgcn_s_barrier();
    __builtin_amdgcn_sched_barrier(0);

    const int c0 = t * 64;
    if (c0 <= q0w + 31) {
      bf16x8 kf[4][2];
#pragma unroll
      for (int ni = 0; ni < 4; ni++) {
        const int row = ni * 16 + lc;
#pragma unroll
        for (int hf = 0; hf < 2; hf++)
          kf[ni][hf] = *reinterpret_cast<const bf16x8*>(
              &Ks[buf][row * 64 + ((((hf * 64 + lg * 16)) ^ (lc7 << 4)) >> 1)]);
      }
      f32x4 sc[4][2] = {};
#pragma unroll
      for (int ni = 0; ni < 4; ni++)
#pragma unroll
        for (int qt = 0; qt < 2; qt++) {
          sc[ni][qt] = __builtin_amdgcn_mfma_f32_16x16x32_bf16(kf[ni][0], qf[qt][0], sc[ni][qt], 0, 0, 0);
          sc[ni][qt] = __builtin_amdgcn_mfma_f32_16x16x32_bf16(kf[ni][1], qf[qt][1], sc[ni][qt], 0, 0, 0);
        }
      bf16x8 vf[4][2];
#pragma unroll
      for (int dt = 0; dt < 4; dt++) {
        const int row = dt * 16 + lc;
#pragma unroll
        for (int ks = 0; ks < 2; ks++)
          vf[dt][ks] = *reinterpret_cast<const bf16x8*>(
              &Vs[buf][row * 64 + (((ks * 64 + lg * 16) ^ (lc7 << 4)) >> 1)]);
      }
      if (c0 + 63 > q0w) {
#pragma unroll
        for (int qt = 0; qt < 2; qt++) {
          const int q = q0w + qt * 16 + lc;
#pragma unroll
          for (int ni = 0; ni < 4; ni++)
#pragma unroll
            for (int rg = 0; rg < 4; rg++)
              if (c0 + ni * 16 + lg * 4 + rg > q) sc[ni][qt][rg] = -1e30f;
        }
      }
      float mx[2];
#pragma unroll
      for (int qt = 0; qt < 2; qt++) {
        float v = -1e30f;
#pragma unroll
        for (int ni = 0; ni < 4; ni++)
#pragma unroll
          for (int rg = 0; rg < 4; rg++) v = fmaxf(v, sc[ni][qt][rg]);
        v = fmaxf(v, __shfl_xor(v, 16));
        v = fmaxf(v, __shfl_xor(v, 32));
        mx[qt] = v;
      }
      if (!__all(mx[0] - mm[0] <= 11.5f && mx[1] - mm[1] <= 11.5f)) {
        float al[2];
#pragma unroll
        for (int qt = 0; qt < 2; qt++) {
          float mn = fmaxf(mm[qt], mx[qt]);
          al[qt] = exp2f(mm[qt] - mn);
          mm[qt] = mn;
          ll[qt] *= al[qt];
        }
#pragma unroll
        for (int qt = 0; qt < 2; qt++)
#pragma unroll
          for (int rg = 0; rg < 4; rg++) {
            float a = __shfl(al[qt], lg * 4 + rg);
#pragma unroll
            for (int dt = 0; dt < 4; dt++) oacc[qt][dt][rg] *= a;
          }
      }
#pragma unroll
      for (int qt = 0; qt < 2; qt++) {
        float rs = 0.0f;
#pragma unroll
        for (int ni = 0; ni < 4; ni++)
#pragma unroll
          for (int rg = 0; rg < 4; rg++) {
            float p = exp2f(sc[ni][qt][rg] - mm[qt]);
            sc[ni][qt][rg] = p;
            rs += p;
          }
        rs += __shfl_xor(rs, 16);
        rs += __shfl_xor(rs, 32);
        ll[qt] += rs;
      }
#pragma unroll
      for (int qt = 0; qt < 2; qt++)
#pragma unroll
        for (int ni = 0; ni < 4; ni++) {
          ushort4 pk;
          pk.x = f2bf(sc[ni][qt][0]);
          pk.y = f2bf(sc[ni][qt][1]);
          pk.z = f2bf(sc[ni][qt][2]);
          pk.w = f2bf(sc[ni][qt][3]);
          *reinterpret_cast<ushort4*>(
              &Pw[(qt * 16 + lc) * 64 + (((ni * 32 + lg * 8) ^ (lc7 << 4)) >> 1)]) = pk;
        }
#pragma unroll
      for (int qt = 0; qt < 2; qt++)
#pragma unroll
        for (int ks = 0; ks < 2; ks++) {
          bf16x8 pa = *reinterpret_cast<const bf16x8*>(
              &Pw[(qt * 16 + lc) * 64 + (((ks * 64 + lg * 16) ^ (lc7 << 4)) >> 1)]);
#pragma unroll
          for (int dt = 0; dt < 4; dt++)
            oacc[qt][dt] = __builtin_amdgcn_mfma_f32_16x16x32_bf16(pa, vf[dt][ks], oacc[qt][dt], 0, 0, 0);
        }
    }
    asm volatile("s_waitcnt lgkmcnt(0)" ::: "memory");
    __builtin_amdgcn_s_barrier();
    __builtin_amdgcn_sched_barrier(0);
    buf ^= 1;
  }
#undef STAGE

#pragma unroll
  for (int qt = 0; qt < 2; qt++) {
    const float li = 1.0f / ll[qt];
#pragma unroll
    for (int rg = 0; rg < 4; rg++) {
      float liq = __shfl(li, lg * 4 + rg);
      int q = q0w + qt * 16 + lg * 4 + rg;
      u16* orow = out + (size_t)(b * SEQ + q) * 1024 + h * 64 + lc;
#pragma unroll
      for (int dt = 0; dt < 4; dt++)
        orow[dt * 16] = f2bf(oacc[qt][dt][rg] * liq);
    }
  }
}

extern "C" void kernel_launch(void* const* d_in, const int* in_sizes, int n_in,
                              void* d_out, int out_size, void* d_ws, size_t ws_size,
                              hipStream_t stream) {
  const float* x = (const float*)d_in[0];
  const float* w_norm1 = (const float*)d_in[1];
  const float* wq = (const float*)d_in[2];
  const float* wk = (const float*)d_in[3];
  const float* wv = (const float*)d_in[4];
  const float* wo = (const float*)d_in[5];
  const float* attn_scale = (const float*)d_in[6];
  const float* w_norm2 = (const float*)d_in[7];
  const float* wg = (const float*)d_in[8];
  const float* wu = (const float*)d_in[9];
  const float* wd = (const float*)d_in[10];
  const float* mlp_scale = (const float*)d_in[11];
  const float* cosb = (const float*)d_in[12];
  const float* sinb = (const float*)d_in[13];
  float* out = (float*)d_out;

  char* ws = (char*)d_ws;
  u16* wqkv_t = (u16*)(ws + 0);            // 1536x1024 bf16
  u16* wo_t = (u16*)(ws + 3145728);        // 1024x1024 bf16
  u16* wg_t = (u16*)(ws + 5242880);        // 4096x1024 bf16
  u16* wu_t = (u16*)(ws + 13631488);
  u16* wd_t = (u16*)(ws + 22020096);       // 1024x4096 bf16
  u16* xn = (u16*)(ws + 30408704);         // 4096x1024 bf16 (reused for xn2)
  float* qkv = (float*)(ws + 38797312);    // 4096x1536 f32
  u16* attn_o = (u16*)(ws + 38797312);     // alias (qkv dead)
  float* x1 = (float*)(ws + 47185920);     // 4096x1024 f32
  u16* q_rope = (u16*)(ws + 63963136);     // 2*16*2048*64 bf16
  u16* k_rope = (u16*)(ws + 72351744);     // 2*4*2048*64 bf16
  u16* vt = (u16*)(ws + 74448896);         // 2*4*64*2048 bf16
  u16* hbuf = (u16*)(ws + 63963136);       // alias (rope dead in FFN phase)

  dim3 tb(256);
  dim3 gb(512);
  transpose_cast_kernel<<<dim3(32, 32), tb, 0, stream>>>(wq, wqkv_t, 1024, 1024);
  transpose_cast_kernel<<<dim3(8, 32), tb, 0, stream>>>(wk, wqkv_t + (size_t)1024 * 1024, 1024, 256);
  transpose_cast_kernel<<<dim3(8, 32), tb, 0, stream>>>(wv, wqkv_t + (size_t)1280 * 1024, 1024, 256);
  transpose_cast_kernel<<<dim3(32, 32), tb, 0, stream>>>(wo, wo_t, 1024, 1024);
  transpose_cast_kernel<<<dim3(128, 32), tb, 0, stream>>>(wg, wg_t, 1024, 4096);
  transpose_cast_kernel<<<dim3(128, 32), tb, 0, stream>>>(wu, wu_t, 1024, 4096);
  transpose_cast_kernel<<<dim3(32, 128), tb, 0, stream>>>(wd, wd_t, 4096, 1024);

  rmsnorm_kernel<<<4096, tb, 0, stream>>>(x, w_norm1, xn);
  gemm256<0><<<dim3(96), gb, 0, stream>>>(xn, wqkv_t, 4096, 1536, 1024, qkv, nullptr, nullptr, nullptr);
  rope_kernel<<<10240, tb, 0, stream>>>(qkv, cosb, sinb, q_rope, k_rope);
  vtrans_kernel<<<2 * 4 * 32, tb, 0, stream>>>(qkv, vt);
  attn_kernel<<<512, tb, 0, stream>>>(q_rope, k_rope, vt, attn_o);
  gemm256<1><<<dim3(64), gb, 0, stream>>>(attn_o, wo_t, 4096, 1024, 1024, x1, x, attn_scale, nullptr);
  rmsnorm_kernel<<<4096, tb, 0, stream>>>(x1, w_norm2, xn);
  gemm256<2><<<dim3(256), gb, 0, stream>>>(xn, wg_t, 4096, 4096, 1024, nullptr, nullptr, nullptr, hbuf);
  gemm256<3><<<dim3(256), gb, 0, stream>>>(xn, wu_t, 4096, 4096, 1024, nullptr, nullptr, nullptr, hbuf);
  gemm256<1><<<dim3(64), gb, 0, stream>>>(hbuf, wd_t, 4096, 1024, 4096, out, x1, mlp_scale, nullptr);
}

// Round 5
// 332.717 us; speedup vs baseline: 1.6825x; 1.1652x over previous
//
#include <hip/hip_runtime.h>
#include <hip/hip_bf16.h>
#include <cstdint>

typedef unsigned short u16;
typedef __attribute__((ext_vector_type(4))) float f32x4;
typedef __attribute__((ext_vector_type(8))) __bf16 bf16x8;

#define NH 16
#define NKV 4
#define SEQ 2048
#define NTOK 4096

__device__ inline u16 f2bf(float f) {
  return __builtin_bit_cast(u16, __float2bfloat16(f));
}
__device__ inline float bf2f(u16 u) {
  return __bfloat162float(__builtin_bit_cast(__hip_bfloat16, u));
}

#define GLDS(gp, lp) __builtin_amdgcn_global_load_lds( \
    (__attribute__((address_space(1))) void*)(gp), \
    (__attribute__((address_space(3))) void*)(lp), 16, 0, 0)

#define VMCNT(n) asm volatile("s_waitcnt vmcnt(" #n ")" ::: "memory")

// ---------------- RMSNorm (f32 in, bf16 out) ----------------
__global__ __launch_bounds__(256) void rmsnorm_kernel(
    const float* __restrict__ x, const float* __restrict__ w,
    u16* __restrict__ out) {
  int row = blockIdx.x;
  int tid = threadIdx.x;
  const float4 v = reinterpret_cast<const float4*>(x + (size_t)row * 1024)[tid];
  float ss = v.x * v.x + v.y * v.y + v.z * v.z + v.w * v.w;
#pragma unroll
  for (int off = 32; off; off >>= 1) ss += __shfl_xor(ss, off);
  __shared__ float red[4];
  int lane = tid & 63, wid = tid >> 6;
  if (lane == 0) red[wid] = ss;
  __syncthreads();
  float tot = red[0] + red[1] + red[2] + red[3];
  float r = rsqrtf(tot * (1.0f / 1024.0f) + 1e-6f);
  const float4 wv = reinterpret_cast<const float4*>(w)[tid];
  ushort4 o;
  o.x = f2bf(v.x * r * wv.x);
  o.y = f2bf(v.y * r * wv.y);
  o.z = f2bf(v.z * r * wv.z);
  o.w = f2bf(v.w * r * wv.w);
  reinterpret_cast<ushort4*>(out + (size_t)row * 1024)[tid] = o;
}

// ---------------- weight transpose + cast: src[K][N] f32 -> dst[N][K] bf16 ----------------
__global__ __launch_bounds__(256) void transpose_cast_kernel(
    const float* __restrict__ src, u16* __restrict__ dst, int K, int N) {
  __shared__ float tile[32][33];
  int n0 = blockIdx.x * 32, k0 = blockIdx.y * 32;
  int tx = threadIdx.x & 31, ty = threadIdx.x >> 5;  // ty: 0..7
#pragma unroll
  for (int i = 0; i < 4; i++)
    tile[ty + i * 8][tx] = src[(size_t)(k0 + ty + i * 8) * N + n0 + tx];
  __syncthreads();
#pragma unroll
  for (int i = 0; i < 4; i++)
    dst[(size_t)(n0 + ty + i * 8) * K + k0 + tx] = f2bf(tile[tx][ty + i * 8]);
}

// ---------------- Pipelined GEMM: C[M][N] = A[M][K] * Bt[N][K]^T, bf16 MFMA ----------------
// BM=256, BN=NB (256 or 128), K-sub phases of 32, 4-slot LDS ring, counted vmcnt.
// EP: 0 f32 out; 1 res+acc*scale f32; 2 silu->bf16; 3 RMW mul bf16.
template <int EP, int NB>
__global__ __launch_bounds__(512, 2) void gemmP(
    const u16* __restrict__ A, const u16* __restrict__ Bt,
    int M, int N, int K,
    float* __restrict__ outf, const float* __restrict__ res,
    const float* __restrict__ scale, u16* __restrict__ outb) {
  constexpr int NTW = NB / 64;          // n-tiles per wave (4 or 2)
  constexpr int SLA = 256 * 32;         // u16 per A sub-slot
  constexpr int SLB = NB * 32;
  __shared__ u16 SA[4][SLA];
  __shared__ u16 SB[4][SLB];

  const int tid = threadIdx.x;
  const int lane = tid & 63;
  const int w = tid >> 6;               // 0..7
  const int wr = w >> 2, wc = w & 3;
  const int lg = lane >> 4, lc = lane & 15;
  const int rsw = (lg ^ (lc & 3)) << 3; // ds_read swizzled chunk (u16 units)

  // XCD-aware rectangle mapping: XCD r8 covers a 4 x (nbn/2) block rectangle
  const int nbn = N / NB;
  const int r8 = blockIdx.x & 7;
  const int j = blockIdx.x >> 3;
  const int bm = (((r8 >> 1) << 2) + (j & 3)) << 8;
  const int bn = ((r8 & 1) * (nbn >> 1) + (j >> 2)) * NB;

  // staging geometry: per GLDS a wave covers 16 rows x 64B; source pre-swizzled
  const int srow = w * 16 + (lane >> 2);          // 0..127
  const int sc = lane & 3;
  const int scs = (sc ^ (srow & 3)) << 3;         // swizzled source col (u16)
  const u16* gA = A + (size_t)(bm + srow) * K + scs;
  const u16* gB = Bt + (size_t)(bn + srow) * K + scs;

#define STAGE(g_) do { \
    const int sl_ = (g_) & 3; \
    const size_t ko_ = (size_t)(g_) * 32; \
    GLDS(gA + ko_, &SA[sl_][(w * 16) * 32]); \
    GLDS(gA + ko_ + (size_t)128 * K, &SA[sl_][(128 + w * 16) * 32]); \
    GLDS(gB + ko_, &SB[sl_][(w * 16) * 32]); \
    if (NB == 256) { GLDS(gB + ko_ + (size_t)128 * K, &SB[sl_][(128 + w * 16) * 32]); } \
  } while (0)

#define PHASE(g_, STG_, VMW_) do { \
    const u16* sa_ = &SA[(g_) & 3][0]; \
    const u16* sb_ = &SB[(g_) & 3][0]; \
    bf16x8 bfr_[NTW]; \
    _Pragma("unroll") for (int jj = 0; jj < NTW; jj++) \
      bfr_[jj] = *reinterpret_cast<const bf16x8*>( \
          &sb_[(wc * (NB / 4) + jj * 16 + lc) * 32 + rsw]); \
    bf16x8 afr_[8]; \
    _Pragma("unroll") for (int ii = 0; ii < 8; ii++) \
      afr_[ii] = *reinterpret_cast<const bf16x8*>( \
          &sa_[(wr * 128 + ii * 16 + lc) * 32 + rsw]); \
    STG_; \
    VMW_; \
    __builtin_amdgcn_s_barrier(); \
    __builtin_amdgcn_s_setprio(1); \
    _Pragma("unroll") for (int ii = 0; ii < 8; ii++) \
      _Pragma("unroll") for (int jj = 0; jj < NTW; jj++) \
        acc[ii][jj] = __builtin_amdgcn_mfma_f32_16x16x32_bf16( \
            afr_[ii], bfr_[jj], acc[ii][jj], 0, 0, 0); \
    __builtin_amdgcn_s_setprio(0); \
    __builtin_amdgcn_s_barrier(); \
  } while (0)

  f32x4 acc[8][NTW] = {};
  const int NSUB = K >> 5;

  // prologue: 3 subs in flight; confirm sub 0 before first read
  STAGE(0);
  STAGE(1);
  STAGE(2);
  if (NB == 256) VMCNT(8); else VMCNT(6);
  __builtin_amdgcn_s_barrier();

  // steady state: stage g+3, confirm <= g+1 (2 stages stay in flight)
  for (int g = 0; g < NSUB - 3; ++g) {
    if (NB == 256) {
      PHASE(g, STAGE(g + 3), VMCNT(8));
    } else {
      PHASE(g, STAGE(g + 3), VMCNT(6));
    }
  }
  // tail: drain 2 -> 1 -> 0 stages
  if (NB == 256) {
    PHASE(NSUB - 3, (void)0, VMCNT(4));
  } else {
    PHASE(NSUB - 3, (void)0, VMCNT(3));
  }
  PHASE(NSUB - 2, (void)0, VMCNT(0));
  PHASE(NSUB - 1, (void)0, (void)0);

#undef PHASE
#undef STAGE

#pragma unroll
  for (int mi = 0; mi < 8; mi++)
#pragma unroll
    for (int ni = 0; ni < NTW; ni++)
#pragma unroll
      for (int rg = 0; rg < 4; rg++) {
        const int row = bm + wr * 128 + mi * 16 + lg * 4 + rg;
        const int col = bn + wc * (NB / 4) + ni * 16 + lc;
        const size_t idx = (size_t)row * N + col;
        const float v = acc[mi][ni][rg];
        if (EP == 0) {
          outf[idx] = v;
        } else if (EP == 1) {
          outf[idx] = res[idx] + v * scale[col];
        } else if (EP == 2) {
          outb[idx] = f2bf(v / (1.0f + __expf(-v)));
        } else {
          outb[idx] = f2bf(bf2f(outb[idx]) * v);
        }
      }
}

// ---------------- RoPE: qkv f32 -> q_rope (pre-scaled by 0.125*log2e) bf16, k_rope bf16 ----------------
__global__ __launch_bounds__(256) void rope_kernel(
    const float* __restrict__ qkv, const float* __restrict__ cosb,
    const float* __restrict__ sinb, u16* __restrict__ qr, u16* __restrict__ kr) {
  int idx = blockIdx.x * 256 + threadIdx.x;  // B*S*20*32 total
  int d = idx & 31;
  int t = idx >> 5;
  int head = t % 20;
  int bs = t / 20;  // 0..4095
  int s = bs & (SEQ - 1);
  int b = bs >> 11;
  const float* row = qkv + (size_t)bs * 1536;
  float c = cosb[s * 32 + d], sn = sinb[s * 32 + d];
  const float QSC = 0.18033688011112042f;  // 0.125 * log2(e)
  float x1, x2;
  if (head < 16) {
    x1 = row[head * 64 + d];
    x2 = row[head * 64 + d + 32];
    size_t o = ((size_t)(b * NH + head) * SEQ + s) * 64 + d;
    qr[o] = f2bf((x1 * c + x2 * sn) * QSC);
    qr[o + 32] = f2bf((x2 * c - x1 * sn) * QSC);
  } else {
    int kh = head - 16;
    x1 = row[1024 + kh * 64 + d];
    x2 = row[1024 + kh * 64 + d + 32];
    size_t o = ((size_t)(b * NKV + kh) * SEQ + s) * 64 + d;
    kr[o] = f2bf(x1 * c + x2 * sn);
    kr[o + 32] = f2bf(x2 * c - x1 * sn);
  }
}

// ---------------- V transpose: qkv f32 -> vt [b][kv][d][s] bf16 ----------------
__global__ __launch_bounds__(256) void vtrans_kernel(
    const float* __restrict__ qkv, u16* __restrict__ vt) {
  int blk = blockIdx.x;
  int st = blk & 31; blk >>= 5;
  int kvh = blk & 3; blk >>= 2;
  int b = blk;
  __shared__ u16 tile[64][65];
  int tx = threadIdx.x & 63;
  int ty = threadIdx.x >> 6;  // 0..3
  int s0 = st * 64;
#pragma unroll
  for (int i = 0; i < 16; i++) {
    int sl = i * 4 + ty;
    tile[sl][tx] = f2bf(qkv[(size_t)(b * SEQ + s0 + sl) * 1536 + 1280 + kvh * 64 + tx]);
  }
  __syncthreads();
  size_t vbase = (size_t)(b * NKV + kvh) * 64 * SEQ;
#pragma unroll
  for (int i = 0; i < 16; i++) {
    int dd = i * 4 + ty;
    vt[vbase + (size_t)dd * SEQ + s0 + tx] = tile[tx][dd];
  }
}

// ---------------- Flash attention v3: 4 waves/block, 32 q-rows/wave, LDS-staged K/V ----------------
__global__ __launch_bounds__(256, 2) void attn_kernel(
    const u16* __restrict__ qr, const u16* __restrict__ kr,
    const u16* __restrict__ vt, u16* __restrict__ out) {
  __shared__ u16 Ks[2][64 * 64];   // [key][d], swizzled
  __shared__ u16 Vs[2][64 * 64];   // [d][key], swizzled
  __shared__ u16 Ps[4][32 * 64];   // per-wave P[q][key], swizzled

  const int n = blockIdx.x;
  const int g = n & 7, m = n >> 3;          // g = b*4+kvh -> XCD-aligned
  const int b = g >> 2, kvh = g & 3;
  const int h = kvh * 4 + (m & 3);
  const int i = m >> 2;                     // 0..15
  const int jb = (i >> 3) ? (15 - (i & 7)) : (i & 7);  // paired for CU balance

  const int tid = threadIdx.x;
  const int lane = tid & 63, w = tid >> 6;
  const int lg = lane >> 4, lc = lane & 15;
  const int lc7 = lc & 7;

  const int q0w = jb * 128 + w * 32;        // wave's first q row
  const int nt = 2 * jb + 2;

  bf16x8 qf[2][2];
  {
    const u16* qp = qr + ((size_t)(b * NH + h) * SEQ + q0w + lc) * 64 + lg * 8;
#pragma unroll
    for (int qt = 0; qt < 2; qt++) {
      qf[qt][0] = *reinterpret_cast<const bf16x8*>(qp + qt * 16 * 64);
      qf[qt][1] = *reinterpret_cast<const bf16x8*>(qp + qt * 16 * 64 + 32);
    }
  }
  asm volatile("s_waitcnt vmcnt(0)" ::: "memory");

  const int r = tid >> 3;
  const int cswz = ((((tid & 7) << 4) ^ ((r & 7) << 4)) >> 1);
  const u16* ksrc = kr + (size_t)(b * NKV + kvh) * SEQ * 64 + r * 64 + cswz;
  const u16* vsrc = vt + ((size_t)(b * NKV + kvh) * 64 + r) * SEQ + cswz;
  u16* Pw = &Ps[w][0];

#define STAGEA(bufi, t) do { \
    const u16* kp_ = ksrc + (size_t)(t) * 64 * 64; \
    const u16* vp_ = vsrc + (size_t)(t) * 64; \
    GLDS(kp_,                 &Ks[bufi][w * 512]); \
    GLDS(kp_ + 32 * 64,       &Ks[bufi][2048 + w * 512]); \
    GLDS(vp_,                 &Vs[bufi][w * 512]); \
    GLDS(vp_ + (size_t)32 * SEQ, &Vs[bufi][2048 + w * 512]); \
  } while (0)

  STAGEA(0, 0);

  float mm[2] = {-1e30f, -1e30f}, ll[2] = {0.0f, 0.0f};
  f32x4 oacc[2][4] = {};

  int buf = 0;
  for (int t = 0; t < nt; ++t) {
    if (t + 1 < nt) {
      STAGEA(buf ^ 1, t + 1);
      asm volatile("s_waitcnt vmcnt(4)" ::: "memory");
    } else {
      asm volatile("s_waitcnt vmcnt(0)" ::: "memory");
    }
    __builtin_amdgcn_s_barrier();
    __builtin_amdgcn_sched_barrier(0);

    const int c0 = t * 64;
    if (c0 <= q0w + 31) {
      bf16x8 kf[4][2];
#pragma unroll
      for (int ni = 0; ni < 4; ni++) {
        const int row = ni * 16 + lc;
#pragma unroll
        for (int hf = 0; hf < 2; hf++)
          kf[ni][hf] = *reinterpret_cast<const bf16x8*>(
              &Ks[buf][row * 64 + ((((hf * 64 + lg * 16)) ^ (lc7 << 4)) >> 1)]);
      }
      f32x4 sc[4][2] = {};
#pragma unroll
      for (int ni = 0; ni < 4; ni++)
#pragma unroll
        for (int qt = 0; qt < 2; qt++) {
          sc[ni][qt] = __builtin_amdgcn_mfma_f32_16x16x32_bf16(kf[ni][0], qf[qt][0], sc[ni][qt], 0, 0, 0);
          sc[ni][qt] = __builtin_amdgcn_mfma_f32_16x16x32_bf16(kf[ni][1], qf[qt][1], sc[ni][qt], 0, 0, 0);
        }
      bf16x8 vf[4][2];
#pragma unroll
      for (int dt = 0; dt < 4; dt++) {
        const int row = dt * 16 + lc;
#pragma unroll
        for (int ks = 0; ks < 2; ks++)
          vf[dt][ks] = *reinterpret_cast<const bf16x8*>(
              &Vs[buf][row * 64 + (((ks * 64 + lg * 16) ^ (lc7 << 4)) >> 1)]);
      }
      if (c0 + 63 > q0w) {
#pragma unroll
        for (int qt = 0; qt < 2; qt++) {
          const int q = q0w + qt * 16 + lc;
#pragma unroll
          for (int ni = 0; ni < 4; ni++)
#pragma unroll
            for (int rg = 0; rg < 4; rg++)
              if (c0 + ni * 16 + lg * 4 + rg > q) sc[ni][qt][rg] = -1e30f;
        }
      }
      float mx[2];
#pragma unroll
      for (int qt = 0; qt < 2; qt++) {
        float v = -1e30f;
#pragma unroll
        for (int ni = 0; ni < 4; ni++)
#pragma unroll
          for (int rg = 0; rg < 4; rg++) v = fmaxf(v, sc[ni][qt][rg]);
        v = fmaxf(v, __shfl_xor(v, 16));
        v = fmaxf(v, __shfl_xor(v, 32));
        mx[qt] = v;
      }
      if (!__all(mx[0] - mm[0] <= 11.5f && mx[1] - mm[1] <= 11.5f)) {
        float al[2];
#pragma unroll
        for (int qt = 0; qt < 2; qt++) {
          float mn = fmaxf(mm[qt], mx[qt]);
          al[qt] = exp2f(mm[qt] - mn);
          mm[qt] = mn;
          ll[qt] *= al[qt];
        }
#pragma unroll
        for (int qt = 0; qt < 2; qt++)
#pragma unroll
          for (int rg = 0; rg < 4; rg++) {
            float a = __shfl(al[qt], lg * 4 + rg);
#pragma unroll
            for (int dt = 0; dt < 4; dt++) oacc[qt][dt][rg] *= a;
          }
      }
#pragma unroll
      for (int qt = 0; qt < 2; qt++) {
        float rs = 0.0f;
#pragma unroll
        for (int ni = 0; ni < 4; ni++)
#pragma unroll
          for (int rg = 0; rg < 4; rg++) {
            float p = exp2f(sc[ni][qt][rg] - mm[qt]);
            sc[ni][qt][rg] = p;
            rs += p;
          }
        rs += __shfl_xor(rs, 16);
        rs += __shfl_xor(rs, 32);
        ll[qt] += rs;
      }
#pragma unroll
      for (int qt = 0; qt < 2; qt++)
#pragma unroll
        for (int ni = 0; ni < 4; ni++) {
          ushort4 pk;
          pk.x = f2bf(sc[ni][qt][0]);
          pk.y = f2bf(sc[ni][qt][1]);
          pk.z = f2bf(sc[ni][qt][2]);
          pk.w = f2bf(sc[ni][qt][3]);
          *reinterpret_cast<ushort4*>(
              &Pw[(qt * 16 + lc) * 64 + (((ni * 32 + lg * 8) ^ (lc7 << 4)) >> 1)]) = pk;
        }
#pragma unroll
      for (int qt = 0; qt < 2; qt++)
#pragma unroll
        for (int ks = 0; ks < 2; ks++) {
          bf16x8 pa = *reinterpret_cast<const bf16x8*>(
              &Pw[(qt * 16 + lc) * 64 + (((ks * 64 + lg * 16) ^ (lc7 << 4)) >> 1)]);
#pragma unroll
          for (int dt = 0; dt < 4; dt++)
            oacc[qt][dt] = __builtin_amdgcn_mfma_f32_16x16x32_bf16(pa, vf[dt][ks], oacc[qt][dt], 0, 0, 0);
        }
    }
    asm volatile("s_waitcnt lgkmcnt(0)" ::: "memory");
    __builtin_amdgcn_s_barrier();
    __builtin_amdgcn_sched_barrier(0);
    buf ^= 1;
  }
#undef STAGEA

#pragma unroll
  for (int qt = 0; qt < 2; qt++) {
    const float li = 1.0f / ll[qt];
#pragma unroll
    for (int rg = 0; rg < 4; rg++) {
      float liq = __shfl(li, lg * 4 + rg);
      int q = q0w + qt * 16 + lg * 4 + rg;
      u16* orow = out + (size_t)(b * SEQ + q) * 1024 + h * 64 + lc;
#pragma unroll
      for (int dt = 0; dt < 4; dt++)
        orow[dt * 16] = f2bf(oacc[qt][dt][rg] * liq);
    }
  }
}

extern "C" void kernel_launch(void* const* d_in, const int* in_sizes, int n_in,
                              void* d_out, int out_size, void* d_ws, size_t ws_size,
                              hipStream_t stream) {
  const float* x = (const float*)d_in[0];
  const float* w_norm1 = (const float*)d_in[1];
  const float* wq = (const float*)d_in[2];
  const float* wk = (const float*)d_in[3];
  const float* wv = (const float*)d_in[4];
  const float* wo = (const float*)d_in[5];
  const float* attn_scale = (const float*)d_in[6];
  const float* w_norm2 = (const float*)d_in[7];
  const float* wg = (const float*)d_in[8];
  const float* wu = (const float*)d_in[9];
  const float* wd = (const float*)d_in[10];
  const float* mlp_scale = (const float*)d_in[11];
  const float* cosb = (const float*)d_in[12];
  const float* sinb = (const float*)d_in[13];
  float* out = (float*)d_out;

  char* ws = (char*)d_ws;
  u16* wqkv_t = (u16*)(ws + 0);            // 1536x1024 bf16
  u16* wo_t = (u16*)(ws + 3145728);        // 1024x1024 bf16
  u16* wg_t = (u16*)(ws + 5242880);        // 4096x1024 bf16
  u16* wu_t = (u16*)(ws + 13631488);
  u16* wd_t = (u16*)(ws + 22020096);       // 1024x4096 bf16
  u16* xn = (u16*)(ws + 30408704);         // 4096x1024 bf16 (reused for xn2)
  float* qkv = (float*)(ws + 38797312);    // 4096x1536 f32
  u16* attn_o = (u16*)(ws + 38797312);     // alias (qkv dead)
  float* x1 = (float*)(ws + 47185920);     // 4096x1024 f32
  u16* q_rope = (u16*)(ws + 63963136);     // 2*16*2048*64 bf16
  u16* k_rope = (u16*)(ws + 72351744);     // 2*4*2048*64 bf16
  u16* vt = (u16*)(ws + 74448896);         // 2*4*64*2048 bf16
  u16* hbuf = (u16*)(ws + 63963136);       // alias (rope dead in FFN phase)

  dim3 tb(256);
  dim3 gb(512);
  transpose_cast_kernel<<<dim3(32, 32), tb, 0, stream>>>(wq, wqkv_t, 1024, 1024);
  transpose_cast_kernel<<<dim3(8, 32), tb, 0, stream>>>(wk, wqkv_t + (size_t)1024 * 1024, 1024, 256);
  transpose_cast_kernel<<<dim3(8, 32), tb, 0, stream>>>(wv, wqkv_t + (size_t)1280 * 1024, 1024, 256);
  transpose_cast_kernel<<<dim3(32, 32), tb, 0, stream>>>(wo, wo_t, 1024, 1024);
  transpose_cast_kernel<<<dim3(128, 32), tb, 0, stream>>>(wg, wg_t, 1024, 4096);
  transpose_cast_kernel<<<dim3(128, 32), tb, 0, stream>>>(wu, wu_t, 1024, 4096);
  transpose_cast_kernel<<<dim3(32, 128), tb, 0, stream>>>(wd, wd_t, 4096, 1024);

  rmsnorm_kernel<<<4096, tb, 0, stream>>>(x, w_norm1, xn);
  gemmP<0, 128><<<dim3(192), gb, 0, stream>>>(xn, wqkv_t, 4096, 1536, 1024, qkv, nullptr, nullptr, nullptr);
  rope_kernel<<<10240, tb, 0, stream>>>(qkv, cosb, sinb, q_rope, k_rope);
  vtrans_kernel<<<2 * 4 * 32, tb, 0, stream>>>(qkv, vt);
  attn_kernel<<<512, tb, 0, stream>>>(q_rope, k_rope, vt, attn_o);
  gemmP<1, 128><<<dim3(128), gb, 0, stream>>>(attn_o, wo_t, 4096, 1024, 1024, x1, x, attn_scale, nullptr);
  rmsnorm_kernel<<<4096, tb, 0, stream>>>(x1, w_norm2, xn);
  gemmP<2, 256><<<dim3(256), gb, 0, stream>>>(xn, wg_t, 4096, 4096, 1024, nullptr, nullptr, nullptr, hbuf);
  gemmP<3, 256><<<dim3(256), gb, 0, stream>>>(xn, wu_t, 4096, 4096, 1024, nullptr, nullptr, nullptr, hbuf);
  gemmP<1, 128><<<dim3(128), gb, 0, stream>>>(hbuf, wd_t, 4096, 1024, 4096, out, x1, mlp_scale, nullptr);
}

// Round 6
// 283.868 us; speedup vs baseline: 1.9720x; 1.1721x over previous
//
#include <hip/hip_runtime.h>
#include <hip/hip_bf16.h>
#include <cstdint>

typedef unsigned short u16;
typedef __attribute__((ext_vector_type(4))) float f32x4;
typedef __attribute__((ext_vector_type(8))) __bf16 bf16x8;

#define NH 16
#define NKV 4
#define SEQ 2048
#define NTOK 4096

__device__ inline u16 f2bf(float f) {
  return __builtin_bit_cast(u16, __float2bfloat16(f));
}
__device__ inline float bf2f(u16 u) {
  return __bfloat162float(__builtin_bit_cast(__hip_bfloat16, u));
}

#define GLDS(gp, lp) __builtin_amdgcn_global_load_lds( \
    (__attribute__((address_space(1))) void*)(gp), \
    (__attribute__((address_space(3))) void*)(lp), 16, 0, 0)

#define VMCNT0 asm volatile("s_waitcnt vmcnt(0)" ::: "memory")

// ---------------- RMSNorm (f32 in, bf16 out) ----------------
__global__ __launch_bounds__(256) void rmsnorm_kernel(
    const float* __restrict__ x, const float* __restrict__ w,
    u16* __restrict__ out) {
  int row = blockIdx.x;
  int tid = threadIdx.x;
  const float4 v = reinterpret_cast<const float4*>(x + (size_t)row * 1024)[tid];
  float ss = v.x * v.x + v.y * v.y + v.z * v.z + v.w * v.w;
#pragma unroll
  for (int off = 32; off; off >>= 1) ss += __shfl_xor(ss, off);
  __shared__ float red[4];
  int lane = tid & 63, wid = tid >> 6;
  if (lane == 0) red[wid] = ss;
  __syncthreads();
  float tot = red[0] + red[1] + red[2] + red[3];
  float r = rsqrtf(tot * (1.0f / 1024.0f) + 1e-6f);
  const float4 wv = reinterpret_cast<const float4*>(w)[tid];
  ushort4 o;
  o.x = f2bf(v.x * r * wv.x);
  o.y = f2bf(v.y * r * wv.y);
  o.z = f2bf(v.z * r * wv.z);
  o.w = f2bf(v.w * r * wv.w);
  reinterpret_cast<ushort4*>(out + (size_t)row * 1024)[tid] = o;
}

// ---------------- weight transpose + cast: src[K][N] f32 -> dst[N][K] bf16 ----------------
__global__ __launch_bounds__(256) void transpose_cast_kernel(
    const float* __restrict__ src, u16* __restrict__ dst, int K, int N) {
  __shared__ float tile[32][33];
  int n0 = blockIdx.x * 32, k0 = blockIdx.y * 32;
  int tx = threadIdx.x & 31, ty = threadIdx.x >> 5;  // ty: 0..7
#pragma unroll
  for (int i = 0; i < 4; i++)
    tile[ty + i * 8][tx] = src[(size_t)(k0 + ty + i * 8) * N + n0 + tx];
  __syncthreads();
#pragma unroll
  for (int i = 0; i < 4; i++)
    dst[(size_t)(n0 + ty + i * 8) * K + k0 + tx] = f2bf(tile[tx][ty + i * 8]);
}

// Shared epilogue
template <int EP>
__device__ inline void epi_store(float v, size_t idx, int col,
                                 float* __restrict__ outf,
                                 const float* __restrict__ res,
                                 const float* __restrict__ scale,
                                 u16* __restrict__ outb) {
  if (EP == 0) {
    outf[idx] = v;
  } else if (EP == 1) {
    outf[idx] = res[idx] + v * scale[col];
  } else if (EP == 2) {
    outb[idx] = f2bf(v / (1.0f + __expf(-v)));
  } else {
    outb[idx] = f2bf(bf2f(outb[idx]) * v);
  }
}

// ---------------- gemmA: 256x256 tile, BK=64, 8 waves, 1 barrier/tile ----------------
// LDS layout: [row][chunk16B], phys_chunk = logical_chunk ^ (row&7)  (8-slot spread)
template <int EP>
__global__ __launch_bounds__(512, 1) void gemmA(
    const u16* __restrict__ A, const u16* __restrict__ Bt,
    int M, int N, int K,
    float* __restrict__ outf, const float* __restrict__ res,
    const float* __restrict__ scale, u16* __restrict__ outb) {
  __shared__ u16 SA[2][256 * 64];
  __shared__ u16 SB[2][256 * 64];
  const int tid = threadIdx.x, lane = tid & 63, w = tid >> 6;
  const int wr = w >> 2, wc = w & 3;
  const int lg = lane >> 4, lc = lane & 15, cx = lc & 7;

  const int nbn = N >> 8;  // 16 for gate/up
  const int r8 = blockIdx.x & 7, j = blockIdx.x >> 3;
  const int bm = (((r8 >> 1) << 2) + (j & 3)) << 8;
  const int bn = ((r8 & 1) * (nbn >> 1) + (j >> 2)) << 8;

  const int swrow = lane >> 3;                 // 0..7
  const int swcol = (lane & 7) ^ swrow;        // pre-swizzled source chunk
  const u16* gA = A + (size_t)(bm + w * 16 + swrow) * K + swcol * 8;
  const u16* gB = Bt + (size_t)(bn + w * 16 + swrow) * K + swcol * 8;

  const int NT = K >> 6;
  f32x4 acc[8][4] = {};

#define SGA(T_) do { int sl_ = (T_) & 1; size_t ko_ = (size_t)(T_) * 64; \
    GLDS(gA + ko_,                    &SA[sl_][(w * 16) * 64]); \
    GLDS(gA + ko_ + (size_t)8 * K,    &SA[sl_][(w * 16 + 8) * 64]); \
    GLDS(gA + ko_ + (size_t)128 * K,  &SA[sl_][(128 + w * 16) * 64]); \
    GLDS(gA + ko_ + (size_t)136 * K,  &SA[sl_][(136 + w * 16) * 64]); } while (0)
#define SGB(T_) do { int sl_ = (T_) & 1; size_t ko_ = (size_t)(T_) * 64; \
    GLDS(gB + ko_,                    &SB[sl_][(w * 16) * 64]); \
    GLDS(gB + ko_ + (size_t)8 * K,    &SB[sl_][(w * 16 + 8) * 64]); \
    GLDS(gB + ko_ + (size_t)128 * K,  &SB[sl_][(128 + w * 16) * 64]); \
    GLDS(gB + ko_ + (size_t)136 * K,  &SB[sl_][(136 + w * 16) * 64]); } while (0)

  SGA(0);
  SGB(0);
  VMCNT0;
  __builtin_amdgcn_s_barrier();

  for (int t = 0; t < NT; ++t) {
    const u16* sa = &SA[t & 1][0];
    const u16* sb = &SB[t & 1][0];
    const bool more = (t + 1 < NT);

    // B fragments: read once, held for the whole tile
    bf16x8 bfr[4][2];
#pragma unroll
    for (int n = 0; n < 4; n++) {
      const int row = wc * 64 + n * 16 + lc;
#pragma unroll
      for (int ks = 0; ks < 2; ks++)
        bfr[n][ks] = *reinterpret_cast<const bf16x8*>(
            &sb[row * 64 + ((((ks << 2) | lg) ^ cx) << 3)]);
    }
    // A fragments m0..3
    bf16x8 afr[4][2];
#pragma unroll
    for (int i = 0; i < 4; i++) {
      const int row = wr * 128 + i * 16 + lc;
#pragma unroll
      for (int ks = 0; ks < 2; ks++)
        afr[i][ks] = *reinterpret_cast<const bf16x8*>(
            &sa[row * 64 + ((((ks << 2) | lg) ^ cx) << 3)]);
    }
    if (more) SGA(t + 1);
    __builtin_amdgcn_s_setprio(1);
#pragma unroll
    for (int i = 0; i < 4; i++)
#pragma unroll
      for (int n = 0; n < 4; n++) {
        acc[i][n] = __builtin_amdgcn_mfma_f32_16x16x32_bf16(afr[i][0], bfr[n][0], acc[i][n], 0, 0, 0);
        acc[i][n] = __builtin_amdgcn_mfma_f32_16x16x32_bf16(afr[i][1], bfr[n][1], acc[i][n], 0, 0, 0);
      }
    __builtin_amdgcn_s_setprio(0);
    // A fragments m4..7
#pragma unroll
    for (int i = 0; i < 4; i++) {
      const int row = wr * 128 + 64 + i * 16 + lc;
#pragma unroll
      for (int ks = 0; ks < 2; ks++)
        afr[i][ks] = *reinterpret_cast<const bf16x8*>(
            &sa[row * 64 + ((((ks << 2) | lg) ^ cx) << 3)]);
    }
    if (more) SGB(t + 1);
    __builtin_amdgcn_s_setprio(1);
#pragma unroll
    for (int i = 0; i < 4; i++)
#pragma unroll
      for (int n = 0; n < 4; n++) {
        acc[4 + i][n] = __builtin_amdgcn_mfma_f32_16x16x32_bf16(afr[i][0], bfr[n][0], acc[4 + i][n], 0, 0, 0);
        acc[4 + i][n] = __builtin_amdgcn_mfma_f32_16x16x32_bf16(afr[i][1], bfr[n][1], acc[4 + i][n], 0, 0, 0);
      }
    __builtin_amdgcn_s_setprio(0);
    VMCNT0;
    __builtin_amdgcn_s_barrier();
  }
#undef SGA
#undef SGB

#pragma unroll
  for (int mi = 0; mi < 8; mi++)
#pragma unroll
    for (int ni = 0; ni < 4; ni++)
#pragma unroll
      for (int rg = 0; rg < 4; rg++) {
        const int row = bm + wr * 128 + mi * 16 + lg * 4 + rg;
        const int col = bn + wc * 64 + ni * 16 + lc;
        epi_store<EP>(acc[mi][ni][rg], (size_t)row * N + col, col, outf, res, scale, outb);
      }
}

// ---------------- gemmB: 128x128 tile, BK=64, 4 waves, 64KB LDS (2 blocks/CU) ----------------
template <int EP>
__global__ __launch_bounds__(256, 1) void gemmB(
    const u16* __restrict__ A, const u16* __restrict__ Bt,
    int M, int N, int K,
    float* __restrict__ outf, const float* __restrict__ res,
    const float* __restrict__ scale, u16* __restrict__ outb) {
  __shared__ u16 SA[2][128 * 64];
  __shared__ u16 SB[2][128 * 64];
  const int tid = threadIdx.x, lane = tid & 63, w = tid >> 6;  // 0..3
  const int wr = w >> 1, wc = w & 1;
  const int lg = lane >> 4, lc = lane & 15, cx = lc & 7;

  const int r8 = blockIdx.x & 7, j = blockIdx.x >> 3;
  const int bm = ((r8 << 2) + (j & 3)) << 7;   // M=4096: 32 m-blocks, 4 per XCD
  const int bn = (j >> 2) << 7;

  const int swrow = lane >> 3;
  const int swcol = (lane & 7) ^ swrow;
  const u16* gA = A + (size_t)(bm + w * 32 + swrow) * K + swcol * 8;
  const u16* gB = Bt + (size_t)(bn + w * 32 + swrow) * K + swcol * 8;

  const int NT = K >> 6;
  f32x4 acc[4][4] = {};

#define SG2(T_) do { int sl_ = (T_) & 1; size_t ko_ = (size_t)(T_) * 64; \
    GLDS(gA + ko_,                   &SA[sl_][(w * 32) * 64]); \
    GLDS(gA + ko_ + (size_t)8 * K,   &SA[sl_][(w * 32 + 8) * 64]); \
    GLDS(gA + ko_ + (size_t)16 * K,  &SA[sl_][(w * 32 + 16) * 64]); \
    GLDS(gA + ko_ + (size_t)24 * K,  &SA[sl_][(w * 32 + 24) * 64]); \
    GLDS(gB + ko_,                   &SB[sl_][(w * 32) * 64]); \
    GLDS(gB + ko_ + (size_t)8 * K,   &SB[sl_][(w * 32 + 8) * 64]); \
    GLDS(gB + ko_ + (size_t)16 * K,  &SB[sl_][(w * 32 + 16) * 64]); \
    GLDS(gB + ko_ + (size_t)24 * K,  &SB[sl_][(w * 32 + 24) * 64]); } while (0)

  SG2(0);
  VMCNT0;
  __builtin_amdgcn_s_barrier();

  for (int t = 0; t < NT; ++t) {
    const u16* sa = &SA[t & 1][0];
    const u16* sb = &SB[t & 1][0];
    const bool more = (t + 1 < NT);

    bf16x8 bfr[4][2], afr[4][2];
#pragma unroll
    for (int n = 0; n < 4; n++) {
      const int row = wc * 64 + n * 16 + lc;
#pragma unroll
      for (int ks = 0; ks < 2; ks++)
        bfr[n][ks] = *reinterpret_cast<const bf16x8*>(
            &sb[row * 64 + ((((ks << 2) | lg) ^ cx) << 3)]);
    }
#pragma unroll
    for (int i = 0; i < 4; i++) {
      const int row = wr * 64 + i * 16 + lc;
#pragma unroll
      for (int ks = 0; ks < 2; ks++)
        afr[i][ks] = *reinterpret_cast<const bf16x8*>(
            &sa[row * 64 + ((((ks << 2) | lg) ^ cx) << 3)]);
    }
    if (more) SG2(t + 1);
    __builtin_amdgcn_s_setprio(1);
#pragma unroll
    for (int i = 0; i < 4; i++)
#pragma unroll
      for (int n = 0; n < 4; n++) {
        acc[i][n] = __builtin_amdgcn_mfma_f32_16x16x32_bf16(afr[i][0], bfr[n][0], acc[i][n], 0, 0, 0);
        acc[i][n] = __builtin_amdgcn_mfma_f32_16x16x32_bf16(afr[i][1], bfr[n][1], acc[i][n], 0, 0, 0);
      }
    __builtin_amdgcn_s_setprio(0);
    VMCNT0;
    __builtin_amdgcn_s_barrier();
  }
#undef SG2

#pragma unroll
  for (int mi = 0; mi < 4; mi++)
#pragma unroll
    for (int ni = 0; ni < 4; ni++)
#pragma unroll
      for (int rg = 0; rg < 4; rg++) {
        const int row = bm + wr * 64 + mi * 16 + lg * 4 + rg;
        const int col = bn + wc * 64 + ni * 16 + lc;
        epi_store<EP>(acc[mi][ni][rg], (size_t)row * N + col, col, outf, res, scale, outb);
      }
}

// ---------------- RoPE: qkv f32 -> q_rope (pre-scaled by 0.125*log2e) bf16, k_rope bf16 ----------------
__global__ __launch_bounds__(256) void rope_kernel(
    const float* __restrict__ qkv, const float* __restrict__ cosb,
    const float* __restrict__ sinb, u16* __restrict__ qr, u16* __restrict__ kr) {
  int idx = blockIdx.x * 256 + threadIdx.x;  // B*S*20*32 total
  int d = idx & 31;
  int t = idx >> 5;
  int head = t % 20;
  int bs = t / 20;  // 0..4095
  int s = bs & (SEQ - 1);
  int b = bs >> 11;
  const float* row = qkv + (size_t)bs * 1536;
  float c = cosb[s * 32 + d], sn = sinb[s * 32 + d];
  const float QSC = 0.18033688011112042f;  // 0.125 * log2(e)
  float x1, x2;
  if (head < 16) {
    x1 = row[head * 64 + d];
    x2 = row[head * 64 + d + 32];
    size_t o = ((size_t)(b * NH + head) * SEQ + s) * 64 + d;
    qr[o] = f2bf((x1 * c + x2 * sn) * QSC);
    qr[o + 32] = f2bf((x2 * c - x1 * sn) * QSC);
  } else {
    int kh = head - 16;
    x1 = row[1024 + kh * 64 + d];
    x2 = row[1024 + kh * 64 + d + 32];
    size_t o = ((size_t)(b * NKV + kh) * SEQ + s) * 64 + d;
    kr[o] = f2bf(x1 * c + x2 * sn);
    kr[o + 32] = f2bf(x2 * c - x1 * sn);
  }
}

// ---------------- V transpose: qkv f32 -> vt [b][kv][d][s] bf16 ----------------
__global__ __launch_bounds__(256) void vtrans_kernel(
    const float* __restrict__ qkv, u16* __restrict__ vt) {
  int blk = blockIdx.x;
  int st = blk & 31; blk >>= 5;
  int kvh = blk & 3; blk >>= 2;
  int b = blk;
  __shared__ u16 tile[64][65];
  int tx = threadIdx.x & 63;
  int ty = threadIdx.x >> 6;  // 0..3
  int s0 = st * 64;
#pragma unroll
  for (int i = 0; i < 16; i++) {
    int sl = i * 4 + ty;
    tile[sl][tx] = f2bf(qkv[(size_t)(b * SEQ + s0 + sl) * 1536 + 1280 + kvh * 64 + tx]);
  }
  __syncthreads();
  size_t vbase = (size_t)(b * NKV + kvh) * 64 * SEQ;
#pragma unroll
  for (int i = 0; i < 16; i++) {
    int dd = i * 4 + ty;
    vt[vbase + (size_t)dd * SEQ + s0 + tx] = tile[tx][dd];
  }
}

// ---------------- Flash attention v3: 4 waves/block, 32 q-rows/wave, LDS-staged K/V ----------------
__global__ __launch_bounds__(256, 2) void attn_kernel(
    const u16* __restrict__ qr, const u16* __restrict__ kr,
    const u16* __restrict__ vt, u16* __restrict__ out) {
  __shared__ u16 Ks[2][64 * 64];   // [key][d], swizzled
  __shared__ u16 Vs[2][64 * 64];   // [d][key], swizzled
  __shared__ u16 Ps[4][32 * 64];   // per-wave P[q][key], swizzled

  const int n = blockIdx.x;
  const int g = n & 7, m = n >> 3;          // g = b*4+kvh -> XCD-aligned
  const int b = g >> 2, kvh = g & 3;
  const int h = kvh * 4 + (m & 3);
  const int i = m >> 2;                     // 0..15
  const int jb = (i >> 3) ? (15 - (i & 7)) : (i & 7);  // paired for CU balance

  const int tid = threadIdx.x;
  const int lane = tid & 63, w = tid >> 6;
  const int lg = lane >> 4, lc = lane & 15;
  const int lc7 = lc & 7;

  const int q0w = jb * 128 + w * 32;        // wave's first q row
  const int nt = 2 * jb + 2;

  bf16x8 qf[2][2];
  {
    const u16* qp = qr + ((size_t)(b * NH + h) * SEQ + q0w + lc) * 64 + lg * 8;
#pragma unroll
    for (int qt = 0; qt < 2; qt++) {
      qf[qt][0] = *reinterpret_cast<const bf16x8*>(qp + qt * 16 * 64);
      qf[qt][1] = *reinterpret_cast<const bf16x8*>(qp + qt * 16 * 64 + 32);
    }
  }
  asm volatile("s_waitcnt vmcnt(0)" ::: "memory");

  const int r = tid >> 3;
  const int cswz = ((((tid & 7) << 4) ^ ((r & 7) << 4)) >> 1);
  const u16* ksrc = kr + (size_t)(b * NKV + kvh) * SEQ * 64 + r * 64 + cswz;
  const u16* vsrc = vt + ((size_t)(b * NKV + kvh) * 64 + r) * SEQ + cswz;
  u16* Pw = &Ps[w][0];

#define STAGEA(bufi, t) do { \
    const u16* kp_ = ksrc + (size_t)(t) * 64 * 64; \
    const u16* vp_ = vsrc + (size_t)(t) * 64; \
    GLDS(kp_,                 &Ks[bufi][w * 512]); \
    GLDS(kp_ + 32 * 64,       &Ks[bufi][2048 + w * 512]); \
    GLDS(vp_,                 &Vs[bufi][w * 512]); \
    GLDS(vp_ + (size_t)32 * SEQ, &Vs[bufi][2048 + w * 512]); \
  } while (0)

  STAGEA(0, 0);

  float mm[2] = {-1e30f, -1e30f}, ll[2] = {0.0f, 0.0f};
  f32x4 oacc[2][4] = {};

  int buf = 0;
  for (int t = 0; t < nt; ++t) {
    if (t + 1 < nt) {
      STAGEA(buf ^ 1, t + 1);
      asm volatile("s_waitcnt vmcnt(4)" ::: "memory");
    } else {
      asm volatile("s_waitcnt vmcnt(0)" ::: "memory");
    }
    __builtin_amdgcn_s_barrier();
    __builtin_amdgcn_sched_barrier(0);

    const int c0 = t * 64;
    if (c0 <= q0w + 31) {
      bf16x8 kf[4][2];
#pragma unroll
      for (int ni = 0; ni < 4; ni++) {
        const int row = ni * 16 + lc;
#pragma unroll
        for (int hf = 0; hf < 2; hf++)
          kf[ni][hf] = *reinterpret_cast<const bf16x8*>(
              &Ks[buf][row * 64 + ((((hf * 64 + lg * 16)) ^ (lc7 << 4)) >> 1)]);
      }
      f32x4 sc[4][2] = {};
#pragma unroll
      for (int ni = 0; ni < 4; ni++)
#pragma unroll
        for (int qt = 0; qt < 2; qt++) {
          sc[ni][qt] = __builtin_amdgcn_mfma_f32_16x16x32_bf16(kf[ni][0], qf[qt][0], sc[ni][qt], 0, 0, 0);
          sc[ni][qt] = __builtin_amdgcn_mfma_f32_16x16x32_bf16(kf[ni][1], qf[qt][1], sc[ni][qt], 0, 0, 0);
        }
      bf16x8 vf[4][2];
#pragma unroll
      for (int dt = 0; dt < 4; dt++) {
        const int row = dt * 16 + lc;
#pragma unroll
        for (int ks = 0; ks < 2; ks++)
          vf[dt][ks] = *reinterpret_cast<const bf16x8*>(
              &Vs[buf][row * 64 + (((ks * 64 + lg * 16) ^ (lc7 << 4)) >> 1)]);
      }
      if (c0 + 63 > q0w) {
#pragma unroll
        for (int qt = 0; qt < 2; qt++) {
          const int q = q0w + qt * 16 + lc;
#pragma unroll
          for (int ni = 0; ni < 4; ni++)
#pragma unroll
            for (int rg = 0; rg < 4; rg++)
              if (c0 + ni * 16 + lg * 4 + rg > q) sc[ni][qt][rg] = -1e30f;
        }
      }
      float mx[2];
#pragma unroll
      for (int qt = 0; qt < 2; qt++) {
        float v = -1e30f;
#pragma unroll
        for (int ni = 0; ni < 4; ni++)
#pragma unroll
          for (int rg = 0; rg < 4; rg++) v = fmaxf(v, sc[ni][qt][rg]);
        v = fmaxf(v, __shfl_xor(v, 16));
        v = fmaxf(v, __shfl_xor(v, 32));
        mx[qt] = v;
      }
      if (!__all(mx[0] - mm[0] <= 11.5f && mx[1] - mm[1] <= 11.5f)) {
        float al[2];
#pragma unroll
        for (int qt = 0; qt < 2; qt++) {
          float mn = fmaxf(mm[qt], mx[qt]);
          al[qt] = exp2f(mm[qt] - mn);
          mm[qt] = mn;
          ll[qt] *= al[qt];
        }
#pragma unroll
        for (int qt = 0; qt < 2; qt++)
#pragma unroll
          for (int rg = 0; rg < 4; rg++) {
            float a = __shfl(al[qt], lg * 4 + rg);
#pragma unroll
            for (int dt = 0; dt < 4; dt++) oacc[qt][dt][rg] *= a;
          }
      }
#pragma unroll
      for (int qt = 0; qt < 2; qt++) {
        float rs = 0.0f;
#pragma unroll
        for (int ni = 0; ni < 4; ni++)
#pragma unroll
          for (int rg = 0; rg < 4; rg++) {
            float p = exp2f(sc[ni][qt][rg] - mm[qt]);
            sc[ni][qt][rg] = p;
            rs += p;
          }
        rs += __shfl_xor(rs, 16);
        rs += __shfl_xor(rs, 32);
        ll[qt] += rs;
      }
#pragma unroll
      for (int qt = 0; qt < 2; qt++)
#pragma unroll
        for (int ni = 0; ni < 4; ni++) {
          ushort4 pk;
          pk.x = f2bf(sc[ni][qt][0]);
          pk.y = f2bf(sc[ni][qt][1]);
          pk.z = f2bf(sc[ni][qt][2]);
          pk.w = f2bf(sc[ni][qt][3]);
          *reinterpret_cast<ushort4*>(
              &Pw[(qt * 16 + lc) * 64 + (((ni * 32 + lg * 8) ^ (lc7 << 4)) >> 1)]) = pk;
        }
#pragma unroll
      for (int qt = 0; qt < 2; qt++)
#pragma unroll
        for (int ks = 0; ks < 2; ks++) {
          bf16x8 pa = *reinterpret_cast<const bf16x8*>(
              &Pw[(qt * 16 + lc) * 64 + (((ks * 64 + lg * 16) ^ (lc7 << 4)) >> 1)]);
#pragma unroll
          for (int dt = 0; dt < 4; dt++)
            oacc[qt][dt] = __builtin_amdgcn_mfma_f32_16x16x32_bf16(pa, vf[dt][ks], oacc[qt][dt], 0, 0, 0);
        }
    }
    asm volatile("s_waitcnt lgkmcnt(0)" ::: "memory");
    __builtin_amdgcn_s_barrier();
    __builtin_amdgcn_sched_barrier(0);
    buf ^= 1;
  }
#undef STAGEA

#pragma unroll
  for (int qt = 0; qt < 2; qt++) {
    const float li = 1.0f / ll[qt];
#pragma unroll
    for (int rg = 0; rg < 4; rg++) {
      float liq = __shfl(li, lg * 4 + rg);
      int q = q0w + qt * 16 + lg * 4 + rg;
      u16* orow = out + (size_t)(b * SEQ + q) * 1024 + h * 64 + lc;
#pragma unroll
      for (int dt = 0; dt < 4; dt++)
        orow[dt * 16] = f2bf(oacc[qt][dt][rg] * liq);
    }
  }
}

extern "C" void kernel_launch(void* const* d_in, const int* in_sizes, int n_in,
                              void* d_out, int out_size, void* d_ws, size_t ws_size,
                              hipStream_t stream) {
  const float* x = (const float*)d_in[0];
  const float* w_norm1 = (const float*)d_in[1];
  const float* wq = (const float*)d_in[2];
  const float* wk = (const float*)d_in[3];
  const float* wv = (const float*)d_in[4];
  const float* wo = (const float*)d_in[5];
  const float* attn_scale = (const float*)d_in[6];
  const float* w_norm2 = (const float*)d_in[7];
  const float* wg = (const float*)d_in[8];
  const float* wu = (const float*)d_in[9];
  const float* wd = (const float*)d_in[10];
  const float* mlp_scale = (const float*)d_in[11];
  const float* cosb = (const float*)d_in[12];
  const float* sinb = (const float*)d_in[13];
  float* out = (float*)d_out;

  char* ws = (char*)d_ws;
  u16* wqkv_t = (u16*)(ws + 0);            // 1536x1024 bf16
  u16* wo_t = (u16*)(ws + 3145728);        // 1024x1024 bf16
  u16* wg_t = (u16*)(ws + 5242880);        // 4096x1024 bf16
  u16* wu_t = (u16*)(ws + 13631488);
  u16* wd_t = (u16*)(ws + 22020096);       // 1024x4096 bf16
  u16* xn = (u16*)(ws + 30408704);         // 4096x1024 bf16 (reused for xn2)
  float* qkv = (float*)(ws + 38797312);    // 4096x1536 f32
  u16* attn_o = (u16*)(ws + 38797312);     // alias (qkv dead)
  float* x1 = (float*)(ws + 47185920);     // 4096x1024 f32
  u16* q_rope = (u16*)(ws + 63963136);     // 2*16*2048*64 bf16
  u16* k_rope = (u16*)(ws + 72351744);     // 2*4*2048*64 bf16
  u16* vt = (u16*)(ws + 74448896);         // 2*4*64*2048 bf16
  u16* hbuf = (u16*)(ws + 63963136);       // alias (rope dead in FFN phase)

  dim3 tb(256);
  transpose_cast_kernel<<<dim3(32, 32), tb, 0, stream>>>(wq, wqkv_t, 1024, 1024);
  transpose_cast_kernel<<<dim3(8, 32), tb, 0, stream>>>(wk, wqkv_t + (size_t)1024 * 1024, 1024, 256);
  transpose_cast_kernel<<<dim3(8, 32), tb, 0, stream>>>(wv, wqkv_t + (size_t)1280 * 1024, 1024, 256);
  transpose_cast_kernel<<<dim3(32, 32), tb, 0, stream>>>(wo, wo_t, 1024, 1024);
  transpose_cast_kernel<<<dim3(128, 32), tb, 0, stream>>>(wg, wg_t, 1024, 4096);
  transpose_cast_kernel<<<dim3(128, 32), tb, 0, stream>>>(wu, wu_t, 1024, 4096);
  transpose_cast_kernel<<<dim3(32, 128), tb, 0, stream>>>(wd, wd_t, 4096, 1024);

  rmsnorm_kernel<<<4096, tb, 0, stream>>>(x, w_norm1, xn);
  gemmB<0><<<dim3(384), dim3(256), 0, stream>>>(xn, wqkv_t, 4096, 1536, 1024, qkv, nullptr, nullptr, nullptr);
  rope_kernel<<<10240, tb, 0, stream>>>(qkv, cosb, sinb, q_rope, k_rope);
  vtrans_kernel<<<2 * 4 * 32, tb, 0, stream>>>(qkv, vt);
  attn_kernel<<<512, tb, 0, stream>>>(q_rope, k_rope, vt, attn_o);
  gemmB<1><<<dim3(256), dim3(256), 0, stream>>>(attn_o, wo_t, 4096, 1024, 1024, x1, x, attn_scale, nullptr);
  rmsnorm_kernel<<<4096, tb, 0, stream>>>(x1, w_norm2, xn);
  gemmA<2><<<dim3(256), dim3(512), 0, stream>>>(xn, wg_t, 4096, 4096, 1024, nullptr, nullptr, nullptr, hbuf);
  gemmA<3><<<dim3(256), dim3(512), 0, stream>>>(xn, wu_t, 4096, 4096, 1024, nullptr, nullptr, nullptr, hbuf);
  gemmB<1><<<dim3(256), dim3(256), 0, stream>>>(hbuf, wd_t, 4096, 1024, 4096, out, x1, mlp_scale, nullptr);
}